// Round 1
// 432.347 us; speedup vs baseline: 1.3385x; 1.3385x over previous
//
#include <hip/hip_runtime.h>
#include <math.h>

// Problem constants
#define BB 4
#define CINC 256
#define COUTC 128
#define HH 64
#define WW 64
#define OHH 128
#define OWW 128

typedef unsigned short u16;
typedef __attribute__((ext_vector_type(8))) short bf16x8;
typedef __attribute__((ext_vector_type(4))) float f32x4;

__device__ __forceinline__ u16 f2bf(float f) {
  unsigned int u = __float_as_uint(f);
  unsigned int r = u + 0x7FFFu + ((u >> 16) & 1u);  // RNE
  return (u16)(r >> 16);
}

// ---------------- K0t: dcn_w [o][c*9+q] -> bf16 wA[o][q*256+c]  (K reordered so a
// 32-wide K-chunk has constant tap q; contiguous k for MFMA A-frags)
__global__ __launch_bounds__(256) void k0t(const float* __restrict__ dcn_w, u16* __restrict__ wA) {
  int tid = blockIdx.x * 256 + threadIdx.x;
  if (tid >= COUTC * CINC * 9) return;
  int o = tid / 2304;
  int ckr = tid - o * 2304;
  int q = ckr >> 8;
  int c = ckr & 255;
  wA[tid] = f2bf(dcn_w[o * 2304 + c * 9 + q]);
}

// ---------------- K0u: transpose up_w -> wt4[tt][i][o][s]
__global__ __launch_bounds__(256) void k0u(const float* __restrict__ up_w, float* __restrict__ wt4) {
  int tid = blockIdx.x * 256 + threadIdx.x;
  if (tid >= 4 * COUTC * COUTC * 4) return;
  int s = tid & 3;
  int o = (tid >> 2) & 127;
  int i = (tid >> 9) & 127;
  int tt = tid >> 16;
  wt4[tid] = up_w[((i * COUTC + o) * 4 + (3 - tt)) * 4 + (3 - s)];
}

// ---------------- K1p: offset conv split-K(8) partials. grid (8,64,4)=(cc,h,b), 256 thr.
__global__ __launch_bounds__(256) void k1p(const float* __restrict__ x,
                                           const float* __restrict__ off_w,
                                           float* __restrict__ part) {
  int cc = blockIdx.x, h = blockIdx.y, b = blockIdx.z;
  __shared__ float xs[3 * 32 * 66];
  int t = threadIdx.x;
  int tw = t & 63;
  int tg = __builtin_amdgcn_readfirstlane(t >> 6);

  float acc[7];
#pragma unroll
  for (int j = 0; j < 7; j++) acc[j] = 0.f;

  int c0 = cc * 32;
  for (int e = t; e < 3 * 32 * 66; e += 256) {
    int r = e / (32 * 66);
    int rem = e - r * (32 * 66);
    int c = rem / 66;
    int wi = rem - c * 66;
    int row = h - 1 + r;
    int col = wi - 1;
    float v = 0.f;
    if (row >= 0 && row < HH && col >= 0 && col < WW)
      v = x[((b * CINC + c0 + c) * HH + row) * WW + col];
    xs[(r * 32 + c) * 66 + wi] = v;
  }
  __syncthreads();
  for (int c = 0; c < 32; c++) {
    float xv[9];
#pragma unroll
    for (int r = 0; r < 3; r++)
#pragma unroll
      for (int dx = 0; dx < 3; dx++)
        xv[r * 3 + dx] = xs[(r * 32 + c) * 66 + tw + dx];
#pragma unroll
    for (int j = 0; j < 7; j++) {
      int oc = tg + 4 * j;
      if (oc < 27) {
        const float* wp = off_w + (oc * CINC + c0 + c) * 9;  // uniform -> s_load
#pragma unroll
        for (int q = 0; q < 9; q++) acc[j] = fmaf(xv[q], wp[q], acc[j]);
      }
    }
  }

#pragma unroll
  for (int j = 0; j < 7; j++) {
    int oc = tg + 4 * j;
    if (oc < 27)
      part[((cc * BB + b) * 27 + oc) * 4096 + h * 64 + tw] = acc[j];
  }
}

// ---------------- K1r: reduce 8 partials + bias -> py/px/m
__global__ __launch_bounds__(256) void k1r(const float* __restrict__ part,
                                           const float* __restrict__ off_b,
                                           float* __restrict__ pyg,
                                           float* __restrict__ pxg,
                                           float* __restrict__ mg) {
  int tid = blockIdx.x * 256 + threadIdx.x;
  if (tid >= BB * 27 * HH * WW) return;
  int w = tid & 63;
  int h = (tid >> 6) & 63;
  int oc = (tid >> 12) % 27;
  int b = tid / (27 * 4096);
  int sp = tid & 4095;

  float v = off_b[oc];
#pragma unroll
  for (int cc = 0; cc < 8; cc++)
    v += part[((cc * BB + b) * 27 + oc) * 4096 + sp];

  int k = oc % 9;
  int gi = ((b * 9 + k) * HH + h) * WW + w;
  if (oc < 9) {
    pyg[gi] = v + (float)(oc / 3) - 1.f + (float)h;
  } else if (oc < 18) {
    pxg[gi] = v + (float)((oc - 9) % 3) - 1.f + (float)w;
  } else {
    mg[gi] = 1.f / (1.f + expf(-v));
  }
}

// ---------------- gather helper: 2 channels x 4 corners
__device__ __forceinline__ void gather8(const float* __restrict__ p0,
                                        int sA0, int sA1, int sB0, int sB1,
                                        float* r) {
  r[0] = p0[sA0]; r[1] = p0[sA1]; r[2] = p0[sB0]; r[3] = p0[sB1];
  const float* p1 = p0 + 4096;
  r[4] = p1[sA0]; r[5] = p1[sA1]; r[6] = p1[sB0]; r[7] = p1[sB1];
}

// ---------------- K2m: deformable conv, split-K(4), bf16 MFMA GEMM.
// grid (4,64,4)=(ks,h,b). Block: 64 px x 128 cout x 64 ch. K reordered ck'=q*256+c:
// each 32-K chunk has constant tap q -> per-thread descriptors (by q, px=t&63) are
// chunk-invariant. Samples gathered f32, packed bf16 into transposed LDS tile
// scolT[px][ck] (stride 40: 16B-aligned b128 B-frags). Weights bf16 from L2 (A-frags).
// LDS double-buffered: ONE barrier per chunk. mfma_f32_16x16x32_bf16, C/D layout
// col=lane&15, row=quad*4+reg (m89-verified).
__global__ __launch_bounds__(256) void k2m(const float* __restrict__ x,
                                           const u16* __restrict__ wA,
                                           const float* __restrict__ pyg,
                                           const float* __restrict__ pxg,
                                           const float* __restrict__ mg,
                                           float* __restrict__ part2) {
  int ks = blockIdx.x, h = blockIdx.y, b = blockIdx.z;
  __shared__ __align__(16) u16 scolT[2][64 * 40];  // [px][ck] bf16, +8 pad
  int t = threadIdx.x;
  int px = t & 63;
  int wave = t >> 6;
  int lane15 = t & 15;
  int quad = (t >> 4) & 3;

  // ---- per-(q,px) bilinear descriptors (masked, m-premultiplied) ----
  float dw0[9], dw1[9], dw2[9], dw3[9];
  int doA[9], doB[9];
#pragma unroll
  for (int q = 0; q < 9; q++) {
    int gi = ((b * 9 + q) * HH + h) * WW + px;
    float py = pyg[gi], pxx = pxg[gi], m = mg[gi];
    float y0f = floorf(py), x0f = floorf(pxx);
    float wy = py - y0f, wx = pxx - x0f;
    int y0 = (int)y0f, x0 = (int)x0f;
    bool vy0 = (unsigned)y0 < 64u, vy1 = (unsigned)(y0 + 1) < 64u;
    bool vx0 = (unsigned)x0 < 64u, vx1 = (unsigned)(x0 + 1) < 64u;
    int y0c = min(max(y0, 0), 63), y1c = min(max(y0 + 1, 0), 63);
    int x0c = min(max(x0, 0), 63), x1c = min(max(x0 + 1, 0), 63);
    dw0[q] = (vy0 && vx0) ? (1.f - wy) * (1.f - wx) * m : 0.f;
    dw1[q] = (vy0 && vx1) ? (1.f - wy) * wx * m : 0.f;
    dw2[q] = (vy1 && vx0) ? wy * (1.f - wx) * m : 0.f;
    dw3[q] = (vy1 && vx1) ? wy * wx * m : 0.f;
    doA[q] = (y0c * 64 + x0c) | ((y0c * 64 + x1c) << 16);
    doB[q] = (y1c * 64 + x0c) | ((y1c * 64 + x1c) << 16);
  }

  f32x4 acc[8];
#pragma unroll
  for (int i = 0; i < 8; i++) acc[i] = (f32x4){0.f, 0.f, 0.f, 0.f};

  const float* xpb = x + b * CINC * 4096;
  const u16* wAr0 = wA + (wave * 32 + lane15) * 2304 + quad * 8;
  const u16* wAr1 = wAr0 + 16 * 2304;

  float rx[32];
  // prefetch chunk 0 (q=0, c0=ks*64)
  {
    int sA0 = doA[0] & 0xffff, sA1 = ((unsigned)doA[0]) >> 16;
    int sB0 = doB[0] & 0xffff, sB1 = ((unsigned)doB[0]) >> 16;
#pragma unroll
    for (int j2 = 0; j2 < 4; j2++)
      gather8(xpb + (ks * 64 + 2 * (wave + 4 * j2)) * 4096, sA0, sA1, sB0, sB1, &rx[8 * j2]);
  }

#pragma unroll
  for (int ci = 0; ci < 18; ci++) {
    int q = ci >> 1;
    // combine prefetched gathers -> bf16 pack -> LDS buf[ci&1]
    u16* sb = &scolT[ci & 1][0];
#pragma unroll
    for (int j2 = 0; j2 < 4; j2++) {
      int u = wave + 4 * j2;
      float vA = dw0[q] * rx[8 * j2 + 0] + dw1[q] * rx[8 * j2 + 1] +
                 dw2[q] * rx[8 * j2 + 2] + dw3[q] * rx[8 * j2 + 3];
      float vB = dw0[q] * rx[8 * j2 + 4] + dw1[q] * rx[8 * j2 + 5] +
                 dw2[q] * rx[8 * j2 + 6] + dw3[q] * rx[8 * j2 + 7];
      *(unsigned*)&sb[px * 40 + 2 * u] = (unsigned)f2bf(vA) | ((unsigned)f2bf(vB) << 16);
    }
    // issue next chunk's gathers (land during barrier+MFMA)
    if (ci < 17) {
      int qn = (ci + 1) >> 1;
      int c0n = ks * 64 + ((ci + 1) & 1) * 32;
      int sA0 = doA[qn] & 0xffff, sA1 = ((unsigned)doA[qn]) >> 16;
      int sB0 = doB[qn] & 0xffff, sB1 = ((unsigned)doB[qn]) >> 16;
#pragma unroll
      for (int j2 = 0; j2 < 4; j2++)
        gather8(xpb + (c0n + 2 * (wave + 4 * j2)) * 4096, sA0, sA1, sB0, sB1, &rx[8 * j2]);
    }
    __syncthreads();  // buf[ci&1] visible; prev reads of buf[(ci-1)&1] drained
    // MFMA: 2 cout rows x 4 px tiles
    int kb = q * 256 + ks * 64 + (ci & 1) * 32;
    bf16x8 a0 = *(const bf16x8*)(wAr0 + kb);
    bf16x8 a1 = *(const bf16x8*)(wAr1 + kb);
    const u16* sr = &scolT[ci & 1][lane15 * 40 + quad * 8];
    bf16x8 b0 = *(const bf16x8*)(sr);
    bf16x8 b1 = *(const bf16x8*)(sr + 16 * 40);
    bf16x8 b2 = *(const bf16x8*)(sr + 32 * 40);
    bf16x8 b3 = *(const bf16x8*)(sr + 48 * 40);
    acc[0] = __builtin_amdgcn_mfma_f32_16x16x32_bf16(a0, b0, acc[0], 0, 0, 0);
    acc[1] = __builtin_amdgcn_mfma_f32_16x16x32_bf16(a0, b1, acc[1], 0, 0, 0);
    acc[2] = __builtin_amdgcn_mfma_f32_16x16x32_bf16(a0, b2, acc[2], 0, 0, 0);
    acc[3] = __builtin_amdgcn_mfma_f32_16x16x32_bf16(a0, b3, acc[3], 0, 0, 0);
    acc[4] = __builtin_amdgcn_mfma_f32_16x16x32_bf16(a1, b0, acc[4], 0, 0, 0);
    acc[5] = __builtin_amdgcn_mfma_f32_16x16x32_bf16(a1, b1, acc[5], 0, 0, 0);
    acc[6] = __builtin_amdgcn_mfma_f32_16x16x32_bf16(a1, b2, acc[6], 0, 0, 0);
    acc[7] = __builtin_amdgcn_mfma_f32_16x16x32_bf16(a1, b3, acc[7], 0, 0, 0);
  }

  // write partials: part2[ks][b][o][h][w]; C/D: col=lane&15 (px), row=quad*4+i (o)
  float* pb = part2 + (size_t)ks * BB * COUTC * 4096;
#pragma unroll
  for (int tr = 0; tr < 2; tr++)
#pragma unroll
    for (int pc = 0; pc < 4; pc++) {
      f32x4 a = acc[tr * 4 + pc];
      int ob = wave * 32 + tr * 16 + quad * 4;
#pragma unroll
      for (int i = 0; i < 4; i++)
        pb[((b * COUTC + ob + i) * HH + h) * WW + pc * 16 + lane15] = a[i];
    }
}

// ---------------- K2r: sum 4 partials + bias -> out1
__global__ __launch_bounds__(256) void k2r(const float* __restrict__ part2,
                                           const float* __restrict__ dcn_b,
                                           float* __restrict__ out1) {
  int tid = blockIdx.x * 256 + threadIdx.x;
  if (tid >= BB * COUTC * HH * WW) return;
  int o = (tid >> 12) & 127;
  const int S = BB * COUTC * 4096;
  out1[tid] = part2[tid] + part2[tid + S] + part2[tid + 2 * S] + part2[tid + 3 * S] + dcn_b[o];
}

// ---------------- BN stats: single-pass split reduction (sum + sumsq).
// grid (C, NCHUNK), 256 thr. float4 loads, wave shuffle reduce + LDS, partials ->
// psum/pssq [C][NCHUNK]. Replaces the old two-pass 128-block stats kernels
// (5% occupancy, 140us for stats2) with ~2048 blocks at full BW.
template <int PLANEF4, int NCHUNK>
__global__ __launch_bounds__(256) void bn_part(const float* __restrict__ src,
                                               float* __restrict__ psum,
                                               float* __restrict__ pssq) {
  int c = blockIdx.x, chunk = blockIdx.y, t = threadIdx.x;
  constexpr int PER = (BB * PLANEF4) / NCHUNK;  // float4s per chunk
  float s = 0.f, s2 = 0.f;
#pragma unroll
  for (int i = 0; i < PER / 256; i++) {
    int f = chunk * PER + i * 256 + t;
    int b = f / PLANEF4;  // compile-time divisor -> shifts
    int sp = f - b * PLANEF4;
    const float4 v = *(const float4*)&src[((size_t)(b * COUTC + c) * PLANEF4 + sp) * 4];
    s += v.x + v.y + v.z + v.w;
    s2 += v.x * v.x + v.y * v.y + v.z * v.z + v.w * v.w;
  }
  // wave reduce (64 lanes)
#pragma unroll
  for (int off = 32; off > 0; off >>= 1) {
    s += __shfl_down(s, off);
    s2 += __shfl_down(s2, off);
  }
  __shared__ float rs[4], rq[4];
  int wv = t >> 6;
  if ((t & 63) == 0) { rs[wv] = s; rq[wv] = s2; }
  __syncthreads();
  if (t == 0) {
    psum[c * NCHUNK + chunk] = rs[0] + rs[1] + rs[2] + rs[3];
    pssq[c * NCHUNK + chunk] = rq[0] + rq[1] + rq[2] + rq[3];
  }
}

// finalize: 1 block x 128 threads; per-channel scale/shift from partials
__global__ __launch_bounds__(128) void bn_fin(const float* __restrict__ psum,
                                              const float* __restrict__ pssq,
                                              const float* __restrict__ g,
                                              const float* __restrict__ bt,
                                              float* __restrict__ scale,
                                              float* __restrict__ shift,
                                              int nchunk, float invN) {
  int c = threadIdx.x;
  float S = 0.f, Q = 0.f;
  for (int i = 0; i < nchunk; i++) {
    S += psum[c * nchunk + i];
    Q += pssq[c * nchunk + i];
  }
  float mu = S * invN;
  float var = Q * invN - mu * mu;
  float sc = g[c] * rsqrtf(var + 1e-5f);
  scale[c] = sc;
  shift[c] = bt[c] - mu * sc;
}

// ---------------- K4f: bn1+relu fused transposed conv (tiled, parity-decomposed).
__global__ __launch_bounds__(256) void k4f(const float* __restrict__ out1,
                                           const float* __restrict__ s1,
                                           const float* __restrict__ sh1,
                                           const float* __restrict__ wt4,
                                           float* __restrict__ out2) {
  int oh = blockIdx.x, b = blockIdx.y;
  __shared__ __align__(16) float ys[2 * 128 * 64];  // exactly 64 KiB
  int t = threadIdx.x;
  int t0 = oh & 1;

#pragma unroll
  for (int ti = 0; ti < 2; ti++) {
    int tt = t0 + 2 * ti;
    int m = (oh + tt - 2) / 2;
    bool rowok = (m >= 0 && m < 64);
    for (int e = t; e < 2048; e += 256) {
      int i = e >> 4;
      float4 v = make_float4(0.f, 0.f, 0.f, 0.f);
      if (rowok) {
        float4 r = *(const float4*)&out1[((b * COUTC + i) * HH + m) * WW + (e & 15) * 4];
        float sc = s1[i], sh = sh1[i];
        v.x = fmaxf(fmaf(r.x, sc, sh), 0.f);
        v.y = fmaxf(fmaf(r.y, sc, sh), 0.f);
        v.z = fmaxf(fmaf(r.z, sc, sh), 0.f);
        v.w = fmaxf(fmaf(r.w, sc, sh), 0.f);
      }
      *(float4*)&ys[ti * 8192 + e * 4] = v;
    }
  }
  __syncthreads();

  int o = t >> 1, half = t & 1;
  int nb = half * 32;
  float acc[64];
#pragma unroll
  for (int j = 0; j < 64; j++) acc[j] = 0.f;

  const float* wb0 = wt4 + ((t0 * 128) * 128 + o) * 4;
  const float* wb1 = wt4 + (((t0 + 2) * 128) * 128 + o) * 4;

  for (int i = 0; i < 128; i++) {
#pragma unroll
    for (int ti = 0; ti < 2; ti++) {
      float4 wv = *(const float4*)((ti ? wb1 : wb0) + i * 512);
      float W0 = wv.x, W1 = wv.y, W2 = wv.z, W3 = wv.w;

      const float* yb = &ys[ti * 8192 + i * 64 + nb];
      float yv[34];
#pragma unroll
      for (int j4 = 0; j4 < 8; j4++) {
        float4 q4 = *(const float4*)(yb + 4 * j4);
        yv[1 + 4 * j4] = q4.x; yv[2 + 4 * j4] = q4.y;
        yv[3 + 4 * j4] = q4.z; yv[4 + 4 * j4] = q4.w;
      }
      yv[0]  = half ? yb[-1] : 0.f;
      yv[33] = half ? 0.f : yb[32];
#pragma unroll
      for (int u = 0; u < 32; u++) {
        acc[2 * u]     = fmaf(W0, yv[u],     fmaf(W2, yv[u + 1], acc[2 * u]));
        acc[2 * u + 1] = fmaf(W1, yv[u + 1], fmaf(W3, yv[u + 2], acc[2 * u + 1]));
      }
    }
  }

  float* op = out2 + ((b * COUTC + o) * OHH + oh) * OWW + half * 64;
#pragma unroll
  for (int j4 = 0; j4 < 16; j4++) {
    float4 v;
    v.x = acc[4 * j4]; v.y = acc[4 * j4 + 1]; v.z = acc[4 * j4 + 2]; v.w = acc[4 * j4 + 3];
    *(float4*)&op[4 * j4] = v;
  }
}

// ---------------- K6: bn2+relu apply (f32 out)
__global__ __launch_bounds__(256) void k6s(const float* __restrict__ out2,
                                           const float* __restrict__ scale2,
                                           const float* __restrict__ shift2,
                                           float* __restrict__ outp) {
  int tid = blockIdx.x * 256 + threadIdx.x;
  if (tid >= BB * COUTC * OHH * OWW) return;
  int c = (tid >> 14) & 127;
  outp[tid] = fmaxf(fmaf(out2[tid], scale2[c], shift2[c]), 0.f);
}

// ---------------- launch
extern "C" void kernel_launch(void* const* d_in, const int* in_sizes, int n_in,
                              void* d_out, int out_size, void* d_ws, size_t ws_size,
                              hipStream_t stream) {
  const float* x     = (const float*)d_in[0];
  const float* off_w = (const float*)d_in[1];
  const float* off_b = (const float*)d_in[2];
  const float* dcn_w = (const float*)d_in[3];
  const float* dcn_b = (const float*)d_in[4];
  const float* bn1_g = (const float*)d_in[5];
  const float* bn1_b = (const float*)d_in[6];
  const float* up_w  = (const float*)d_in[7];
  const float* bn2_g = (const float*)d_in[8];
  const float* bn2_b = (const float*)d_in[9];

  float* ws = (float*)d_ws;
  float* pyg  = ws;                              // 147456
  float* pxg  = pyg + BB * 9 * HH * WW;          // 147456
  float* mg   = pxg + BB * 9 * HH * WW;          // 147456
  float* out1 = mg + BB * 9 * HH * WW;           // 2097152
  float* scale1 = out1 + BB * COUTC * HH * WW;   // 128
  float* shift1 = scale1 + 128;                  // 128
  float* out2 = shift1 + 128;                    // 8388608
  float* scale2 = out2 + BB * COUTC * OHH * OWW; // 128
  float* shift2 = scale2 + 128;                  // 128
  float* w_t = shift2 + 128;                     // 294912 floats reserved (wA uses half as u16)
  float* wt4 = w_t + COUTC * CINC * 9;           // 262144
  float* part2 = wt4 + 4 * COUTC * COUTC * 4;    // 4 * 2097152
  u16* wA = (u16*)w_t;                           // 128*2304 bf16
  // k1 partials (8*4*27*4096 = 3.5M floats) overlaid on out2 region
  float* part = out2;
  // bn stats partials overlaid on part2 (dead after k2r)
  float* psum = part2;            // up to 128*16
  float* pssq = part2 + 128 * 16; // up to 128*16

  const int N4 = BB * COUTC * OHH * OWW;  // 8388608
  const int N2 = BB * COUTC * HH * WW;    // 2097152
  const int N1 = BB * 27 * HH * WW;       // 442368

  k0t<<<(COUTC * CINC * 9 + 255) / 256, 256, 0, stream>>>(dcn_w, wA);
  k0u<<<(4 * COUTC * COUTC * 4 + 255) / 256, 256, 0, stream>>>(up_w, wt4);
  k1p<<<dim3(8, 64, 4), 256, 0, stream>>>(x, off_w, part);
  k1r<<<(N1 + 255) / 256, 256, 0, stream>>>(part, off_b, pyg, pxg, mg);
  k2m<<<dim3(4, 64, 4), 256, 0, stream>>>(x, wA, pyg, pxg, mg, part2);
  k2r<<<(N2 + 255) / 256, 256, 0, stream>>>(part2, dcn_b, out1);
  // bn1 stats: out1 plane = 4096 f32 = 1024 float4; 8 chunks -> 1024 blocks
  bn_part<1024, 8><<<dim3(COUTC, 8), 256, 0, stream>>>(out1, psum, pssq);
  bn_fin<<<1, 128, 0, stream>>>(psum, pssq, bn1_g, bn1_b, scale1, shift1, 8,
                                1.f / 16384.f);
  k4f<<<dim3(128, 4), 256, 0, stream>>>(out1, scale1, shift1, wt4, out2);
  // bn2 stats: out2 plane = 16384 f32 = 4096 float4; 16 chunks -> 2048 blocks
  bn_part<4096, 16><<<dim3(COUTC, 16), 256, 0, stream>>>(out2, psum, pssq);
  bn_fin<<<1, 128, 0, stream>>>(psum, pssq, bn2_g, bn2_b, scale2, shift2, 16,
                                1.f / 65536.f);
  k6s<<<(N4 + 255) / 256, 256, 0, stream>>>(out2, scale2, shift2, (float*)d_out);
}

// Round 2
// 339.909 us; speedup vs baseline: 1.7025x; 1.2720x over previous
//
#include <hip/hip_runtime.h>
#include <math.h>

// Problem constants
#define BB 4
#define CINC 256
#define COUTC 128
#define HH 64
#define WW 64
#define OHH 128
#define OWW 128

typedef unsigned short u16;
typedef __attribute__((ext_vector_type(8))) short bf16x8;
typedef __attribute__((ext_vector_type(4))) float f32x4;

__device__ __forceinline__ u16 f2bf(float f) {
  unsigned int u = __float_as_uint(f);
  unsigned int r = u + 0x7FFFu + ((u >> 16) & 1u);  // RNE
  return (u16)(r >> 16);
}

// ---------------- K0t: dcn_w [o][c*9+q] -> bf16 wA[o][q*256+c]  (K reordered so a
// 32-wide K-chunk has constant tap q; contiguous k for MFMA A-frags)
__global__ __launch_bounds__(256) void k0t(const float* __restrict__ dcn_w, u16* __restrict__ wA) {
  int tid = blockIdx.x * 256 + threadIdx.x;
  if (tid >= COUTC * CINC * 9) return;
  int o = tid / 2304;
  int ckr = tid - o * 2304;
  int q = ckr >> 8;
  int c = ckr & 255;
  wA[tid] = f2bf(dcn_w[o * 2304 + c * 9 + q]);
}

// ---------------- K4w: pack up_w into 4 parity-class bf16 A-matrices.
// Apk[pq][o][k'], k' = (ky*2+kx)*128 + i  (tap-major: each 32-K chunk tap-uniform).
// A[pq][o][k'] = up_w[i][o][3-(p+2ky)][3-(q+2kx)]  (wf = flip+transpose of up_w).
__global__ __launch_bounds__(256) void k4w(const float* __restrict__ up_w, u16* __restrict__ Apk) {
  int tid = blockIdx.x * 256 + threadIdx.x;
  if (tid >= 4 * COUTC * 512) return;
  int kp = tid & 511;
  int o = (tid >> 9) & 127;
  int pq = tid >> 16;
  int p = pq >> 1, q = pq & 1;
  int ky = kp >> 8, kx = (kp >> 7) & 1, i = kp & 127;
  float v = up_w[((i * COUTC + o) * 4 + (3 - (p + 2 * ky))) * 4 + (3 - (q + 2 * kx))];
  Apk[tid] = f2bf(v);
}

// ---------------- K1p: offset conv split-K(8) partials. grid (8,64,4)=(cc,h,b), 256 thr.
__global__ __launch_bounds__(256) void k1p(const float* __restrict__ x,
                                           const float* __restrict__ off_w,
                                           float* __restrict__ part) {
  int cc = blockIdx.x, h = blockIdx.y, b = blockIdx.z;
  __shared__ float xs[3 * 32 * 66];
  int t = threadIdx.x;
  int tw = t & 63;
  int tg = __builtin_amdgcn_readfirstlane(t >> 6);

  float acc[7];
#pragma unroll
  for (int j = 0; j < 7; j++) acc[j] = 0.f;

  int c0 = cc * 32;
  for (int e = t; e < 3 * 32 * 66; e += 256) {
    int r = e / (32 * 66);
    int rem = e - r * (32 * 66);
    int c = rem / 66;
    int wi = rem - c * 66;
    int row = h - 1 + r;
    int col = wi - 1;
    float v = 0.f;
    if (row >= 0 && row < HH && col >= 0 && col < WW)
      v = x[((b * CINC + c0 + c) * HH + row) * WW + col];
    xs[(r * 32 + c) * 66 + wi] = v;
  }
  __syncthreads();
  for (int c = 0; c < 32; c++) {
    float xv[9];
#pragma unroll
    for (int r = 0; r < 3; r++)
#pragma unroll
      for (int dx = 0; dx < 3; dx++)
        xv[r * 3 + dx] = xs[(r * 32 + c) * 66 + tw + dx];
#pragma unroll
    for (int j = 0; j < 7; j++) {
      int oc = tg + 4 * j;
      if (oc < 27) {
        const float* wp = off_w + (oc * CINC + c0 + c) * 9;  // uniform -> s_load
#pragma unroll
        for (int q = 0; q < 9; q++) acc[j] = fmaf(xv[q], wp[q], acc[j]);
      }
    }
  }

#pragma unroll
  for (int j = 0; j < 7; j++) {
    int oc = tg + 4 * j;
    if (oc < 27)
      part[((cc * BB + b) * 27 + oc) * 4096 + h * 64 + tw] = acc[j];
  }
}

// ---------------- K1r: reduce 8 partials + bias -> py/px/m
__global__ __launch_bounds__(256) void k1r(const float* __restrict__ part,
                                           const float* __restrict__ off_b,
                                           float* __restrict__ pyg,
                                           float* __restrict__ pxg,
                                           float* __restrict__ mg) {
  int tid = blockIdx.x * 256 + threadIdx.x;
  if (tid >= BB * 27 * HH * WW) return;
  int w = tid & 63;
  int h = (tid >> 6) & 63;
  int oc = (tid >> 12) % 27;
  int b = tid / (27 * 4096);
  int sp = tid & 4095;

  float v = off_b[oc];
#pragma unroll
  for (int cc = 0; cc < 8; cc++)
    v += part[((cc * BB + b) * 27 + oc) * 4096 + sp];

  int k = oc % 9;
  int gi = ((b * 9 + k) * HH + h) * WW + w;
  if (oc < 9) {
    pyg[gi] = v + (float)(oc / 3) - 1.f + (float)h;
  } else if (oc < 18) {
    pxg[gi] = v + (float)((oc - 9) % 3) - 1.f + (float)w;
  } else {
    mg[gi] = 1.f / (1.f + expf(-v));
  }
}

// ---------------- gather helper: 2 channels x 4 corners
__device__ __forceinline__ void gather8(const float* __restrict__ p0,
                                        int sA0, int sA1, int sB0, int sB1,
                                        float* r) {
  r[0] = p0[sA0]; r[1] = p0[sA1]; r[2] = p0[sB0]; r[3] = p0[sB1];
  const float* p1 = p0 + 4096;
  r[4] = p1[sA0]; r[5] = p1[sA1]; r[6] = p1[sB0]; r[7] = p1[sB1];
}

// ---------------- K2m: deformable conv, split-K(4), bf16 MFMA GEMM.
// grid (4,64,4)=(ks,h,b). Block: 64 px x 128 cout x 64 ch. K reordered ck'=q*256+c:
// each 32-K chunk has constant tap q -> per-thread descriptors (by q, px=t&63) are
// chunk-invariant. Samples gathered f32, packed bf16 into transposed LDS tile
// scolT[px][ck] (stride 40: 16B-aligned b128 B-frags). Weights bf16 from L2 (A-frags).
// LDS double-buffered: ONE barrier per chunk. mfma_f32_16x16x32_bf16, C/D layout
// col=lane&15, row=quad*4+reg (m89-verified).
__global__ __launch_bounds__(256) void k2m(const float* __restrict__ x,
                                           const u16* __restrict__ wA,
                                           const float* __restrict__ pyg,
                                           const float* __restrict__ pxg,
                                           const float* __restrict__ mg,
                                           float* __restrict__ part2) {
  int ks = blockIdx.x, h = blockIdx.y, b = blockIdx.z;
  __shared__ __align__(16) u16 scolT[2][64 * 40];  // [px][ck] bf16, +8 pad
  int t = threadIdx.x;
  int px = t & 63;
  int wave = t >> 6;
  int lane15 = t & 15;
  int quad = (t >> 4) & 3;

  // ---- per-(q,px) bilinear descriptors (masked, m-premultiplied) ----
  float dw0[9], dw1[9], dw2[9], dw3[9];
  int doA[9], doB[9];
#pragma unroll
  for (int q = 0; q < 9; q++) {
    int gi = ((b * 9 + q) * HH + h) * WW + px;
    float py = pyg[gi], pxx = pxg[gi], m = mg[gi];
    float y0f = floorf(py), x0f = floorf(pxx);
    float wy = py - y0f, wx = pxx - x0f;
    int y0 = (int)y0f, x0 = (int)x0f;
    bool vy0 = (unsigned)y0 < 64u, vy1 = (unsigned)(y0 + 1) < 64u;
    bool vx0 = (unsigned)x0 < 64u, vx1 = (unsigned)(x0 + 1) < 64u;
    int y0c = min(max(y0, 0), 63), y1c = min(max(y0 + 1, 0), 63);
    int x0c = min(max(x0, 0), 63), x1c = min(max(x0 + 1, 0), 63);
    dw0[q] = (vy0 && vx0) ? (1.f - wy) * (1.f - wx) * m : 0.f;
    dw1[q] = (vy0 && vx1) ? (1.f - wy) * wx * m : 0.f;
    dw2[q] = (vy1 && vx0) ? wy * (1.f - wx) * m : 0.f;
    dw3[q] = (vy1 && vx1) ? wy * wx * m : 0.f;
    doA[q] = (y0c * 64 + x0c) | ((y0c * 64 + x1c) << 16);
    doB[q] = (y1c * 64 + x0c) | ((y1c * 64 + x1c) << 16);
  }

  f32x4 acc[8];
#pragma unroll
  for (int i = 0; i < 8; i++) acc[i] = (f32x4){0.f, 0.f, 0.f, 0.f};

  const float* xpb = x + b * CINC * 4096;
  const u16* wAr0 = wA + (wave * 32 + lane15) * 2304 + quad * 8;
  const u16* wAr1 = wAr0 + 16 * 2304;

  float rx[32];
  // prefetch chunk 0 (q=0, c0=ks*64)
  {
    int sA0 = doA[0] & 0xffff, sA1 = ((unsigned)doA[0]) >> 16;
    int sB0 = doB[0] & 0xffff, sB1 = ((unsigned)doB[0]) >> 16;
#pragma unroll
    for (int j2 = 0; j2 < 4; j2++)
      gather8(xpb + (ks * 64 + 2 * (wave + 4 * j2)) * 4096, sA0, sA1, sB0, sB1, &rx[8 * j2]);
  }

#pragma unroll
  for (int ci = 0; ci < 18; ci++) {
    int q = ci >> 1;
    // combine prefetched gathers -> bf16 pack -> LDS buf[ci&1]
    u16* sb = &scolT[ci & 1][0];
#pragma unroll
    for (int j2 = 0; j2 < 4; j2++) {
      int u = wave + 4 * j2;
      float vA = dw0[q] * rx[8 * j2 + 0] + dw1[q] * rx[8 * j2 + 1] +
                 dw2[q] * rx[8 * j2 + 2] + dw3[q] * rx[8 * j2 + 3];
      float vB = dw0[q] * rx[8 * j2 + 4] + dw1[q] * rx[8 * j2 + 5] +
                 dw2[q] * rx[8 * j2 + 6] + dw3[q] * rx[8 * j2 + 7];
      *(unsigned*)&sb[px * 40 + 2 * u] = (unsigned)f2bf(vA) | ((unsigned)f2bf(vB) << 16);
    }
    // issue next chunk's gathers (land during barrier+MFMA)
    if (ci < 17) {
      int qn = (ci + 1) >> 1;
      int c0n = ks * 64 + ((ci + 1) & 1) * 32;
      int sA0 = doA[qn] & 0xffff, sA1 = ((unsigned)doA[qn]) >> 16;
      int sB0 = doB[qn] & 0xffff, sB1 = ((unsigned)doB[qn]) >> 16;
#pragma unroll
      for (int j2 = 0; j2 < 4; j2++)
        gather8(xpb + (c0n + 2 * (wave + 4 * j2)) * 4096, sA0, sA1, sB0, sB1, &rx[8 * j2]);
    }
    __syncthreads();  // buf[ci&1] visible; prev reads of buf[(ci-1)&1] drained
    // MFMA: 2 cout rows x 4 px tiles
    int kb = q * 256 + ks * 64 + (ci & 1) * 32;
    bf16x8 a0 = *(const bf16x8*)(wAr0 + kb);
    bf16x8 a1 = *(const bf16x8*)(wAr1 + kb);
    const u16* sr = &scolT[ci & 1][lane15 * 40 + quad * 8];
    bf16x8 b0 = *(const bf16x8*)(sr);
    bf16x8 b1 = *(const bf16x8*)(sr + 16 * 40);
    bf16x8 b2 = *(const bf16x8*)(sr + 32 * 40);
    bf16x8 b3 = *(const bf16x8*)(sr + 48 * 40);
    acc[0] = __builtin_amdgcn_mfma_f32_16x16x32_bf16(a0, b0, acc[0], 0, 0, 0);
    acc[1] = __builtin_amdgcn_mfma_f32_16x16x32_bf16(a0, b1, acc[1], 0, 0, 0);
    acc[2] = __builtin_amdgcn_mfma_f32_16x16x32_bf16(a0, b2, acc[2], 0, 0, 0);
    acc[3] = __builtin_amdgcn_mfma_f32_16x16x32_bf16(a0, b3, acc[3], 0, 0, 0);
    acc[4] = __builtin_amdgcn_mfma_f32_16x16x32_bf16(a1, b0, acc[4], 0, 0, 0);
    acc[5] = __builtin_amdgcn_mfma_f32_16x16x32_bf16(a1, b1, acc[5], 0, 0, 0);
    acc[6] = __builtin_amdgcn_mfma_f32_16x16x32_bf16(a1, b2, acc[6], 0, 0, 0);
    acc[7] = __builtin_amdgcn_mfma_f32_16x16x32_bf16(a1, b3, acc[7], 0, 0, 0);
  }

  // write partials: part2[ks][b][o][h][w]; C/D: col=lane&15 (px), row=quad*4+i (o)
  float* pb = part2 + (size_t)ks * BB * COUTC * 4096;
#pragma unroll
  for (int tr = 0; tr < 2; tr++)
#pragma unroll
    for (int pc = 0; pc < 4; pc++) {
      f32x4 a = acc[tr * 4 + pc];
      int ob = wave * 32 + tr * 16 + quad * 4;
#pragma unroll
      for (int i = 0; i < 4; i++)
        pb[((b * COUTC + ob + i) * HH + h) * WW + pc * 16 + lane15] = a[i];
    }
}

// ---------------- K2r: sum 4 partials + bias -> out1
__global__ __launch_bounds__(256) void k2r(const float* __restrict__ part2,
                                           const float* __restrict__ dcn_b,
                                           float* __restrict__ out1) {
  int tid = blockIdx.x * 256 + threadIdx.x;
  if (tid >= BB * COUTC * HH * WW) return;
  int o = (tid >> 12) & 127;
  const int S = BB * COUTC * 4096;
  out1[tid] = part2[tid] + part2[tid + S] + part2[tid + 2 * S] + part2[tid + 3 * S] + dcn_b[o];
}

// ---------------- BN stats: single-pass split reduction (sum + sumsq).
template <int PLANEF4, int NCHUNK>
__global__ __launch_bounds__(256) void bn_part(const float* __restrict__ src,
                                               float* __restrict__ psum,
                                               float* __restrict__ pssq) {
  int c = blockIdx.x, chunk = blockIdx.y, t = threadIdx.x;
  constexpr int PER = (BB * PLANEF4) / NCHUNK;  // float4s per chunk
  float s = 0.f, s2 = 0.f;
#pragma unroll
  for (int i = 0; i < PER / 256; i++) {
    int f = chunk * PER + i * 256 + t;
    int b = f / PLANEF4;  // compile-time divisor -> shifts
    int sp = f - b * PLANEF4;
    const float4 v = *(const float4*)&src[((size_t)(b * COUTC + c) * PLANEF4 + sp) * 4];
    s += v.x + v.y + v.z + v.w;
    s2 += v.x * v.x + v.y * v.y + v.z * v.z + v.w * v.w;
  }
#pragma unroll
  for (int off = 32; off > 0; off >>= 1) {
    s += __shfl_down(s, off);
    s2 += __shfl_down(s2, off);
  }
  __shared__ float rs[4], rq[4];
  int wv = t >> 6;
  if ((t & 63) == 0) { rs[wv] = s; rq[wv] = s2; }
  __syncthreads();
  if (t == 0) {
    psum[c * NCHUNK + chunk] = rs[0] + rs[1] + rs[2] + rs[3];
    pssq[c * NCHUNK + chunk] = rq[0] + rq[1] + rq[2] + rq[3];
  }
}

// finalize: 1 block x 128 threads; per-channel scale/shift from partials
__global__ __launch_bounds__(128) void bn_fin(const float* __restrict__ psum,
                                              const float* __restrict__ pssq,
                                              const float* __restrict__ g,
                                              const float* __restrict__ bt,
                                              float* __restrict__ scale,
                                              float* __restrict__ shift,
                                              int nchunk, float invN) {
  int c = threadIdx.x;
  float S = 0.f, Q = 0.f;
  for (int i = 0; i < nchunk; i++) {
    S += psum[c * nchunk + i];
    Q += pssq[c * nchunk + i];
  }
  float mu = S * invN;
  float var = Q * invN - mu * mu;
  float sc = g[c] * rsqrtf(var + 1e-5f);
  scale[c] = sc;
  shift[c] = bt[c] - mu * sc;
}

// ---------------- K4a: bn1+relu apply, bf16 convert, channel-last transpose.
// out1[b][c][m][w] f32 -> yT[b][m][w][c] bf16. grid (64 m, 4 b), 256 thr.
__global__ __launch_bounds__(256) void k4a(const float* __restrict__ out1,
                                           const float* __restrict__ s1,
                                           const float* __restrict__ sh1,
                                           u16* __restrict__ yT) {
  int m = blockIdx.x, b = blockIdx.y;
  __shared__ __align__(16) u16 T2[64 * 136];
  int t = threadIdx.x;
  for (int e = t; e < 2048; e += 256) {
    int w4 = e & 15, c = e >> 4;
    float4 r = *(const float4*)&out1[((b * COUTC + c) * HH + m) * WW + w4 * 4];
    float sc = s1[c], sh = sh1[c];
    T2[(w4 * 4 + 0) * 136 + c] = f2bf(fmaxf(fmaf(r.x, sc, sh), 0.f));
    T2[(w4 * 4 + 1) * 136 + c] = f2bf(fmaxf(fmaf(r.y, sc, sh), 0.f));
    T2[(w4 * 4 + 2) * 136 + c] = f2bf(fmaxf(fmaf(r.z, sc, sh), 0.f));
    T2[(w4 * 4 + 3) * 136 + c] = f2bf(fmaxf(fmaf(r.w, sc, sh), 0.f));
  }
  __syncthreads();
  for (int e = t; e < 1024; e += 256) {
    int g2 = e * 8;
    int w = g2 >> 7, i = g2 & 127;
    *(bf16x8*)&yT[((size_t)(b * 64 + m) * 64 + w) * 128 + i] =
        *(const bf16x8*)&T2[w * 136 + i];
  }
}

// ---------------- K4m: transposed conv as bf16 MFMA GEMM.
// grid (128 oh, 4 b). Block: one output row oh (parity p=oh&1), all 128 ow (both
// col-parities q), 128 couts. K = 512 per q class = (ky,kx) taps x 128 ch.
// B-tile T[ky][pxp=66][c=128] bf16 (stride 136 u16 = 68 dw -> 2-way bank alias,
// free). Column shifts (q+kx) are ds_read pointer offsets into the shared tile;
// border cols pxp=0,65 pre-zeroed. ONE barrier total; 1024 MFMAs/block.
// Epilogue interleaves q0/q1 accs into coalesced float2 stores.
__global__ __launch_bounds__(256) void k4m(const u16* __restrict__ yT,
                                           const u16* __restrict__ Apk,
                                           float* __restrict__ out2) {
  int oh = blockIdx.x, b = blockIdx.y;
  int a = oh >> 1, p = oh & 1;
  __shared__ __align__(16) u16 T[2][66 * 136];
  int t = threadIdx.x;
  int wave = t >> 6, lane15 = t & 15, quad = (t >> 4) & 3;

  // zero border cols: 2 bufs x 2 cols x 128 ch
  for (int e = t; e < 512; e += 256) {
    int ky = e >> 8;
    int rem = e & 255;
    int colp = (rem >> 7) * 65;
    int i = rem & 127;
    T[ky][colp * 136 + i] = 0;
  }
  // stage both tap rows (r = a+p+ky-1); contiguous 16KB copy each
#pragma unroll
  for (int ky = 0; ky < 2; ky++) {
    int r = a + p + ky - 1;
    bool ok = ((unsigned)r < 64u);
    const u16* src = yT + ((size_t)(b * 64 + r) * 64) * 128;
#pragma unroll
    for (int it = 0; it < 4; it++) {
      int g2 = (it * 256 + t) * 8;
      int col = g2 >> 7, i = g2 & 127;
      bf16x8 v = (bf16x8){0, 0, 0, 0, 0, 0, 0, 0};
      if (ok) v = *(const bf16x8*)(src + g2);
      *(bf16x8*)&T[ky][(col + 1) * 136 + i] = v;
    }
  }
  __syncthreads();

  f32x4 acc[2][2][4];  // [q][tr][pc]
#pragma unroll
  for (int q = 0; q < 2; q++)
#pragma unroll
    for (int tr = 0; tr < 2; tr++)
#pragma unroll
      for (int pc = 0; pc < 4; pc++) acc[q][tr][pc] = (f32x4){0.f, 0.f, 0.f, 0.f};

  int row0 = wave * 32 + lane15;
  const u16* A0 = Apk + ((size_t)(p * 2 + 0) * 128) * 512;
  const u16* A1 = Apk + ((size_t)(p * 2 + 1) * 128) * 512;

#pragma unroll
  for (int ky = 0; ky < 2; ky++)
#pragma unroll
    for (int kx = 0; kx < 2; kx++)
#pragma unroll
      for (int c4 = 0; c4 < 4; c4++) {
        int kb = (ky * 2 + kx) * 128 + c4 * 32 + quad * 8;
        bf16x8 a00 = *(const bf16x8*)(A0 + (size_t)row0 * 512 + kb);
        bf16x8 a01 = *(const bf16x8*)(A0 + (size_t)(row0 + 16) * 512 + kb);
        bf16x8 a10 = *(const bf16x8*)(A1 + (size_t)row0 * 512 + kb);
        bf16x8 a11 = *(const bf16x8*)(A1 + (size_t)(row0 + 16) * 512 + kb);
        const u16* tb = &T[ky][(lane15 + kx) * 136 + c4 * 32 + quad * 8];
#pragma unroll
        for (int pc = 0; pc < 4; pc++) {
          bf16x8 b0 = *(const bf16x8*)(tb + (pc * 16) * 136);
          bf16x8 b1 = *(const bf16x8*)(tb + (pc * 16 + 1) * 136);
          acc[0][0][pc] = __builtin_amdgcn_mfma_f32_16x16x32_bf16(a00, b0, acc[0][0][pc], 0, 0, 0);
          acc[0][1][pc] = __builtin_amdgcn_mfma_f32_16x16x32_bf16(a01, b0, acc[0][1][pc], 0, 0, 0);
          acc[1][0][pc] = __builtin_amdgcn_mfma_f32_16x16x32_bf16(a10, b1, acc[1][0][pc], 0, 0, 0);
          acc[1][1][pc] = __builtin_amdgcn_mfma_f32_16x16x32_bf16(a11, b1, acc[1][1][pc], 0, 0, 0);
        }
      }

  // epilogue: C/D col=lane&15 (px), row=quad*4+i (cout). ow = 2*px + q -> float2.
#pragma unroll
  for (int tr = 0; tr < 2; tr++) {
    int o0 = wave * 32 + tr * 16 + quad * 4;
#pragma unroll
    for (int pc = 0; pc < 4; pc++) {
      f32x4 v0 = acc[0][tr][pc];
      f32x4 v1 = acc[1][tr][pc];
      int cw = pc * 32 + 2 * lane15;
#pragma unroll
      for (int i = 0; i < 4; i++) {
        float2 w2;
        w2.x = v0[i];
        w2.y = v1[i];
        *(float2*)&out2[(((size_t)b * COUTC + o0 + i) * OHH + oh) * OWW + cw] = w2;
      }
    }
  }
}

// ---------------- K6: bn2+relu apply (f32 out)
__global__ __launch_bounds__(256) void k6s(const float* __restrict__ out2,
                                           const float* __restrict__ scale2,
                                           const float* __restrict__ shift2,
                                           float* __restrict__ outp) {
  int tid = blockIdx.x * 256 + threadIdx.x;
  if (tid >= BB * COUTC * OHH * OWW) return;
  int c = (tid >> 14) & 127;
  outp[tid] = fmaxf(fmaf(out2[tid], scale2[c], shift2[c]), 0.f);
}

// ---------------- launch
extern "C" void kernel_launch(void* const* d_in, const int* in_sizes, int n_in,
                              void* d_out, int out_size, void* d_ws, size_t ws_size,
                              hipStream_t stream) {
  const float* x     = (const float*)d_in[0];
  const float* off_w = (const float*)d_in[1];
  const float* off_b = (const float*)d_in[2];
  const float* dcn_w = (const float*)d_in[3];
  const float* dcn_b = (const float*)d_in[4];
  const float* bn1_g = (const float*)d_in[5];
  const float* bn1_b = (const float*)d_in[6];
  const float* up_w  = (const float*)d_in[7];
  const float* bn2_g = (const float*)d_in[8];
  const float* bn2_b = (const float*)d_in[9];

  float* ws = (float*)d_ws;
  float* pyg  = ws;                              // 147456
  float* pxg  = pyg + BB * 9 * HH * WW;          // 147456
  float* mg   = pxg + BB * 9 * HH * WW;          // 147456
  float* out1 = mg + BB * 9 * HH * WW;           // 2097152
  float* scale1 = out1 + BB * COUTC * HH * WW;   // 128
  float* shift1 = scale1 + 128;                  // 128
  float* out2 = shift1 + 128;                    // 8388608
  float* scale2 = out2 + BB * COUTC * OHH * OWW; // 128
  float* shift2 = scale2 + 128;                  // 128
  float* w_t = shift2 + 128;                     // 294912 floats reserved (wA uses half as u16)
  float* wt4 = w_t + COUTC * CINC * 9;           // 262144 floats (Apk uses as u16)
  float* part2 = wt4 + 4 * COUTC * COUTC * 4;    // 4 * 2097152
  u16* wA = (u16*)w_t;                           // 128*2304 bf16
  u16* Apk = (u16*)wt4;                          // 4*128*512 bf16 = 512KB
  // k1 partials (8*4*27*4096 = 3.5M floats) overlaid on out2 region
  float* part = out2;
  // bn stats partials overlaid on part2 start (dead after k2r)
  float* psum = part2;            // up to 128*16
  float* pssq = part2 + 128 * 16; // up to 128*16
  // yT (bf16 4MB) overlaid past the stats partials in the part2 region
  u16* yT = (u16*)(part2 + 8192);

  const int N4 = BB * COUTC * OHH * OWW;  // 8388608
  const int N2 = BB * COUTC * HH * WW;    // 2097152
  const int N1 = BB * 27 * HH * WW;       // 442368

  k0t<<<(COUTC * CINC * 9 + 255) / 256, 256, 0, stream>>>(dcn_w, wA);
  k4w<<<(4 * COUTC * 512 + 255) / 256, 256, 0, stream>>>(up_w, Apk);
  k1p<<<dim3(8, 64, 4), 256, 0, stream>>>(x, off_w, part);
  k1r<<<(N1 + 255) / 256, 256, 0, stream>>>(part, off_b, pyg, pxg, mg);
  k2m<<<dim3(4, 64, 4), 256, 0, stream>>>(x, wA, pyg, pxg, mg, part2);
  k2r<<<(N2 + 255) / 256, 256, 0, stream>>>(part2, dcn_b, out1);
  // bn1 stats
  bn_part<1024, 8><<<dim3(COUTC, 8), 256, 0, stream>>>(out1, psum, pssq);
  bn_fin<<<1, 128, 0, stream>>>(psum, pssq, bn1_g, bn1_b, scale1, shift1, 8,
                                1.f / 16384.f);
  // bn1 apply + transpose to bf16 channel-last
  k4a<<<dim3(64, 4), 256, 0, stream>>>(out1, scale1, shift1, yT);
  // transposed conv via MFMA
  k4m<<<dim3(128, 4), 256, 0, stream>>>(yT, Apk, out2);
  // bn2 stats
  bn_part<4096, 16><<<dim3(COUTC, 16), 256, 0, stream>>>(out2, psum, pssq);
  bn_fin<<<1, 128, 0, stream>>>(psum, pssq, bn2_g, bn2_b, scale2, shift2, 16,
                                1.f / 65536.f);
  k6s<<<(N4 + 255) / 256, 256, 0, stream>>>(out2, scale2, shift2, (float*)d_out);
}

// Round 3
// 325.659 us; speedup vs baseline: 1.7770x; 1.0438x over previous
//
#include <hip/hip_runtime.h>
#include <math.h>

// Problem constants
#define BB 4
#define CINC 256
#define COUTC 128
#define HH 64
#define WW 64
#define OHH 128
#define OWW 128

typedef unsigned short u16;
typedef __attribute__((ext_vector_type(8))) short bf16x8;
typedef __attribute__((ext_vector_type(4))) float f32x4;

__device__ __forceinline__ u16 f2bf(float f) {
  unsigned int u = __float_as_uint(f);
  unsigned int r = u + 0x7FFFu + ((u >> 16) & 1u);  // RNE
  return (u16)(r >> 16);
}

// ---------------- K0t: dcn_w [o][c*9+q] -> bf16 wA[o][q*256+c]  (K reordered so a
// 32-wide K-chunk has constant tap q; contiguous k for MFMA A-frags)
__global__ __launch_bounds__(256) void k0t(const float* __restrict__ dcn_w, u16* __restrict__ wA) {
  int tid = blockIdx.x * 256 + threadIdx.x;
  if (tid >= COUTC * CINC * 9) return;
  int o = tid / 2304;
  int ckr = tid - o * 2304;
  int q = ckr >> 8;
  int c = ckr & 255;
  wA[tid] = f2bf(dcn_w[o * 2304 + c * 9 + q]);
}

// ---------------- K4w: pack up_w into 4 parity-class bf16 A-matrices.
// Apk[pq][o][k'], k' = (ky*2+kx)*128 + i  (tap-major: each 32-K chunk tap-uniform).
__global__ __launch_bounds__(256) void k4w(const float* __restrict__ up_w, u16* __restrict__ Apk) {
  int tid = blockIdx.x * 256 + threadIdx.x;
  if (tid >= 4 * COUTC * 512) return;
  int kp = tid & 511;
  int o = (tid >> 9) & 127;
  int pq = tid >> 16;
  int p = pq >> 1, q = pq & 1;
  int ky = kp >> 8, kx = (kp >> 7) & 1, i = kp & 127;
  float v = up_w[((i * COUTC + o) * 4 + (3 - (p + 2 * ky))) * 4 + (3 - (q + 2 * kx))];
  Apk[tid] = f2bf(v);
}

// ---------------- K2t: transpose x[b][c][y][w] -> xT[b][y][w][c] (f32, channel-last).
// grid (64 y, 4 cq, 4 b), 256 thr. LDS 64x65 tile; both sides coalesced 256B.
__global__ __launch_bounds__(256) void k2t(const float* __restrict__ x, float* __restrict__ xT) {
  int y = blockIdx.x, cq = blockIdx.y, b = blockIdx.z;
  __shared__ float tile[64][65];
  int t = threadIdx.x;
  int tx = t & 63;
  int tg = t >> 6;
#pragma unroll
  for (int i = 0; i < 16; i++) {
    int c = tg * 16 + i;
    tile[c][tx] = x[((size_t)(b * CINC + cq * 64 + c) * HH + y) * WW + tx];
  }
  __syncthreads();
#pragma unroll
  for (int i = 0; i < 16; i++) {
    int xc = tg * 16 + i;
    xT[((size_t)(b * HH + y) * WW + xc) * CINC + cq * 64 + tx] = tile[tx][xc];
  }
}

// ---------------- K1p: offset conv split-K(8) partials. grid (8,64,4)=(cc,h,b), 256 thr.
__global__ __launch_bounds__(256) void k1p(const float* __restrict__ x,
                                           const float* __restrict__ off_w,
                                           float* __restrict__ part) {
  int cc = blockIdx.x, h = blockIdx.y, b = blockIdx.z;
  __shared__ float xs[3 * 32 * 66];
  int t = threadIdx.x;
  int tw = t & 63;
  int tg = __builtin_amdgcn_readfirstlane(t >> 6);

  float acc[7];
#pragma unroll
  for (int j = 0; j < 7; j++) acc[j] = 0.f;

  int c0 = cc * 32;
  for (int e = t; e < 3 * 32 * 66; e += 256) {
    int r = e / (32 * 66);
    int rem = e - r * (32 * 66);
    int c = rem / 66;
    int wi = rem - c * 66;
    int row = h - 1 + r;
    int col = wi - 1;
    float v = 0.f;
    if (row >= 0 && row < HH && col >= 0 && col < WW)
      v = x[((b * CINC + c0 + c) * HH + row) * WW + col];
    xs[(r * 32 + c) * 66 + wi] = v;
  }
  __syncthreads();
  for (int c = 0; c < 32; c++) {
    float xv[9];
#pragma unroll
    for (int r = 0; r < 3; r++)
#pragma unroll
      for (int dx = 0; dx < 3; dx++)
        xv[r * 3 + dx] = xs[(r * 32 + c) * 66 + tw + dx];
#pragma unroll
    for (int j = 0; j < 7; j++) {
      int oc = tg + 4 * j;
      if (oc < 27) {
        const float* wp = off_w + (oc * CINC + c0 + c) * 9;  // uniform -> s_load
#pragma unroll
        for (int q = 0; q < 9; q++) acc[j] = fmaf(xv[q], wp[q], acc[j]);
      }
    }
  }

#pragma unroll
  for (int j = 0; j < 7; j++) {
    int oc = tg + 4 * j;
    if (oc < 27)
      part[((cc * BB + b) * 27 + oc) * 4096 + h * 64 + tw] = acc[j];
  }
}

// ---------------- K1r: reduce 8 partials + bias -> py/px/m
__global__ __launch_bounds__(256) void k1r(const float* __restrict__ part,
                                           const float* __restrict__ off_b,
                                           float* __restrict__ pyg,
                                           float* __restrict__ pxg,
                                           float* __restrict__ mg) {
  int tid = blockIdx.x * 256 + threadIdx.x;
  if (tid >= BB * 27 * HH * WW) return;
  int w = tid & 63;
  int h = (tid >> 6) & 63;
  int oc = (tid >> 12) % 27;
  int b = tid / (27 * 4096);
  int sp = tid & 4095;

  float v = off_b[oc];
#pragma unroll
  for (int cc = 0; cc < 8; cc++)
    v += part[((cc * BB + b) * 27 + oc) * 4096 + sp];

  int k = oc % 9;
  int gi = ((b * 9 + k) * HH + h) * WW + w;
  if (oc < 9) {
    pyg[gi] = v + (float)(oc / 3) - 1.f + (float)h;
  } else if (oc < 18) {
    pxg[gi] = v + (float)((oc - 9) % 3) - 1.f + (float)w;
  } else {
    mg[gi] = 1.f / (1.f + expf(-v));
  }
}

// ---------------- gather: 4 corners x 8 contiguous channels from channel-last xT.
// base = xT + b-plane + channel offset; s* are spatial element indices (y*64+x).
__device__ __forceinline__ void gatherC(const float* __restrict__ base,
                                        int sA0, int sA1, int sB0, int sB1,
                                        f32x4* rx) {
  const float* pA0 = base + (size_t)sA0 * CINC;
  const float* pA1 = base + (size_t)sA1 * CINC;
  const float* pB0 = base + (size_t)sB0 * CINC;
  const float* pB1 = base + (size_t)sB1 * CINC;
  rx[0] = *(const f32x4*)pA0;
  rx[1] = *(const f32x4*)(pA0 + 4);
  rx[2] = *(const f32x4*)pA1;
  rx[3] = *(const f32x4*)(pA1 + 4);
  rx[4] = *(const f32x4*)pB0;
  rx[5] = *(const f32x4*)(pB0 + 4);
  rx[6] = *(const f32x4*)pB1;
  rx[7] = *(const f32x4*)(pB1 + 4);
}

// ---------------- K2m: deformable conv, split-K(4), bf16 MFMA GEMM.
// grid (4,64,4)=(ks,h,b). Block: 64 px x 128 cout x 64 ch. K reordered ck'=q*256+c.
// NEW: x gathered from channel-last xT — each thread fetches 8 channels per corner
// via 2x dwordx4 (4 corners -> 8 vector loads vs 32 scalar). Pack-writes are one
// b128 per thread (conflict-free bank tiling at stride 40 u16). LDS double-buffered,
// ONE barrier per chunk. mfma_f32_16x16x32_bf16, C/D col=lane&15, row=quad*4+reg.
__global__ __launch_bounds__(256) void k2m(const float* __restrict__ xT,
                                           const u16* __restrict__ wA,
                                           const float* __restrict__ pyg,
                                           const float* __restrict__ pxg,
                                           const float* __restrict__ mg,
                                           float* __restrict__ part2) {
  int ks = blockIdx.x, h = blockIdx.y, b = blockIdx.z;
  __shared__ __align__(16) u16 scolT[2][64 * 40];  // [px][ck] bf16, +8 pad
  int t = threadIdx.x;
  int px = t & 63;
  int wave = t >> 6;
  int lane15 = t & 15;
  int quad = (t >> 4) & 3;

  // ---- per-(q,px) bilinear descriptors (masked, m-premultiplied) ----
  float dw0[9], dw1[9], dw2[9], dw3[9];
  int doA[9], doB[9];
#pragma unroll
  for (int q = 0; q < 9; q++) {
    int gi = ((b * 9 + q) * HH + h) * WW + px;
    float py = pyg[gi], pxx = pxg[gi], m = mg[gi];
    float y0f = floorf(py), x0f = floorf(pxx);
    float wy = py - y0f, wx = pxx - x0f;
    int y0 = (int)y0f, x0 = (int)x0f;
    bool vy0 = (unsigned)y0 < 64u, vy1 = (unsigned)(y0 + 1) < 64u;
    bool vx0 = (unsigned)x0 < 64u, vx1 = (unsigned)(x0 + 1) < 64u;
    int y0c = min(max(y0, 0), 63), y1c = min(max(y0 + 1, 0), 63);
    int x0c = min(max(x0, 0), 63), x1c = min(max(x0 + 1, 0), 63);
    dw0[q] = (vy0 && vx0) ? (1.f - wy) * (1.f - wx) * m : 0.f;
    dw1[q] = (vy0 && vx1) ? (1.f - wy) * wx * m : 0.f;
    dw2[q] = (vy1 && vx0) ? wy * (1.f - wx) * m : 0.f;
    dw3[q] = (vy1 && vx1) ? wy * wx * m : 0.f;
    doA[q] = (y0c * 64 + x0c) | ((y0c * 64 + x1c) << 16);
    doB[q] = (y1c * 64 + x0c) | ((y1c * 64 + x1c) << 16);
  }

  f32x4 acc[8];
#pragma unroll
  for (int i = 0; i < 8; i++) acc[i] = (f32x4){0.f, 0.f, 0.f, 0.f};

  const float* xTb = xT + (size_t)b * 4096 * CINC;
  const u16* wAr0 = wA + (wave * 32 + lane15) * 2304 + quad * 8;
  const u16* wAr1 = wAr0 + 16 * 2304;

  f32x4 rx[8];
  // prefetch chunk 0 (q=0, channels ks*64 + wave*8)
  gatherC(xTb + ks * 64 + wave * 8, doA[0] & 0xffff, ((unsigned)doA[0]) >> 16,
          doB[0] & 0xffff, ((unsigned)doB[0]) >> 16, rx);

#pragma unroll
  for (int ci = 0; ci < 18; ci++) {
    int q = ci >> 1;
    // combine prefetched corner vectors -> bf16 pack -> one b128 LDS write
    float v[8];
#pragma unroll
    for (int j = 0; j < 4; j++) {
      v[j]     = dw0[q] * rx[0][j] + dw1[q] * rx[2][j] + dw2[q] * rx[4][j] + dw3[q] * rx[6][j];
      v[4 + j] = dw0[q] * rx[1][j] + dw1[q] * rx[3][j] + dw2[q] * rx[5][j] + dw3[q] * rx[7][j];
    }
    uint4 st;
    st.x = (unsigned)f2bf(v[0]) | ((unsigned)f2bf(v[1]) << 16);
    st.y = (unsigned)f2bf(v[2]) | ((unsigned)f2bf(v[3]) << 16);
    st.z = (unsigned)f2bf(v[4]) | ((unsigned)f2bf(v[5]) << 16);
    st.w = (unsigned)f2bf(v[6]) | ((unsigned)f2bf(v[7]) << 16);
    *(uint4*)&scolT[ci & 1][px * 40 + wave * 8] = st;

    // issue next chunk's gathers (land during barrier+MFMA)
    if (ci < 17) {
      int qn = (ci + 1) >> 1;
      int c0n = ks * 64 + ((ci + 1) & 1) * 32 + wave * 8;
      gatherC(xTb + c0n, doA[qn] & 0xffff, ((unsigned)doA[qn]) >> 16,
              doB[qn] & 0xffff, ((unsigned)doB[qn]) >> 16, rx);
    }
    __syncthreads();  // buf[ci&1] visible; prev reads of buf[(ci-1)&1] drained
    // MFMA: 2 cout rows x 4 px tiles
    int kb = q * 256 + ks * 64 + (ci & 1) * 32;
    bf16x8 a0 = *(const bf16x8*)(wAr0 + kb);
    bf16x8 a1 = *(const bf16x8*)(wAr1 + kb);
    const u16* sr = &scolT[ci & 1][lane15 * 40 + quad * 8];
    bf16x8 b0 = *(const bf16x8*)(sr);
    bf16x8 b1 = *(const bf16x8*)(sr + 16 * 40);
    bf16x8 b2 = *(const bf16x8*)(sr + 32 * 40);
    bf16x8 b3 = *(const bf16x8*)(sr + 48 * 40);
    acc[0] = __builtin_amdgcn_mfma_f32_16x16x32_bf16(a0, b0, acc[0], 0, 0, 0);
    acc[1] = __builtin_amdgcn_mfma_f32_16x16x32_bf16(a0, b1, acc[1], 0, 0, 0);
    acc[2] = __builtin_amdgcn_mfma_f32_16x16x32_bf16(a0, b2, acc[2], 0, 0, 0);
    acc[3] = __builtin_amdgcn_mfma_f32_16x16x32_bf16(a0, b3, acc[3], 0, 0, 0);
    acc[4] = __builtin_amdgcn_mfma_f32_16x16x32_bf16(a1, b0, acc[4], 0, 0, 0);
    acc[5] = __builtin_amdgcn_mfma_f32_16x16x32_bf16(a1, b1, acc[5], 0, 0, 0);
    acc[6] = __builtin_amdgcn_mfma_f32_16x16x32_bf16(a1, b2, acc[6], 0, 0, 0);
    acc[7] = __builtin_amdgcn_mfma_f32_16x16x32_bf16(a1, b3, acc[7], 0, 0, 0);
  }

  // write partials: part2[ks][b][o][h][w]; C/D: col=lane&15 (px), row=quad*4+i (o)
  float* pb = part2 + (size_t)ks * BB * COUTC * 4096;
#pragma unroll
  for (int tr = 0; tr < 2; tr++)
#pragma unroll
    for (int pc = 0; pc < 4; pc++) {
      f32x4 a = acc[tr * 4 + pc];
      int ob = wave * 32 + tr * 16 + quad * 4;
#pragma unroll
      for (int i = 0; i < 4; i++)
        pb[((b * COUTC + ob + i) * HH + h) * WW + pc * 16 + lane15] = a[i];
    }
}

// ---------------- K2r: sum 4 partials + bias -> out1
__global__ __launch_bounds__(256) void k2r(const float* __restrict__ part2,
                                           const float* __restrict__ dcn_b,
                                           float* __restrict__ out1) {
  int tid = blockIdx.x * 256 + threadIdx.x;
  if (tid >= BB * COUTC * HH * WW) return;
  int o = (tid >> 12) & 127;
  const int S = BB * COUTC * 4096;
  out1[tid] = part2[tid] + part2[tid + S] + part2[tid + 2 * S] + part2[tid + 3 * S] + dcn_b[o];
}

// ---------------- BN stats: single-pass split reduction (sum + sumsq).
template <int PLANEF4, int NCHUNK>
__global__ __launch_bounds__(256) void bn_part(const float* __restrict__ src,
                                               float* __restrict__ psum,
                                               float* __restrict__ pssq) {
  int c = blockIdx.x, chunk = blockIdx.y, t = threadIdx.x;
  constexpr int PER = (BB * PLANEF4) / NCHUNK;  // float4s per chunk
  float s = 0.f, s2 = 0.f;
#pragma unroll
  for (int i = 0; i < PER / 256; i++) {
    int f = chunk * PER + i * 256 + t;
    int b = f / PLANEF4;  // compile-time divisor -> shifts
    int sp = f - b * PLANEF4;
    const float4 v = *(const float4*)&src[((size_t)(b * COUTC + c) * PLANEF4 + sp) * 4];
    s += v.x + v.y + v.z + v.w;
    s2 += v.x * v.x + v.y * v.y + v.z * v.z + v.w * v.w;
  }
#pragma unroll
  for (int off = 32; off > 0; off >>= 1) {
    s += __shfl_down(s, off);
    s2 += __shfl_down(s2, off);
  }
  __shared__ float rs[4], rq[4];
  int wv = t >> 6;
  if ((t & 63) == 0) { rs[wv] = s; rq[wv] = s2; }
  __syncthreads();
  if (t == 0) {
    psum[c * NCHUNK + chunk] = rs[0] + rs[1] + rs[2] + rs[3];
    pssq[c * NCHUNK + chunk] = rq[0] + rq[1] + rq[2] + rq[3];
  }
}

// finalize: 1 block x 128 threads; per-channel scale/shift from partials
__global__ __launch_bounds__(128) void bn_fin(const float* __restrict__ psum,
                                              const float* __restrict__ pssq,
                                              const float* __restrict__ g,
                                              const float* __restrict__ bt,
                                              float* __restrict__ scale,
                                              float* __restrict__ shift,
                                              int nchunk, float invN) {
  int c = threadIdx.x;
  float S = 0.f, Q = 0.f;
  for (int i = 0; i < nchunk; i++) {
    S += psum[c * nchunk + i];
    Q += pssq[c * nchunk + i];
  }
  float mu = S * invN;
  float var = Q * invN - mu * mu;
  float sc = g[c] * rsqrtf(var + 1e-5f);
  scale[c] = sc;
  shift[c] = bt[c] - mu * sc;
}

// ---------------- K4a: bn1+relu apply, bf16 convert, channel-last transpose.
// out1[b][c][m][w] f32 -> yT[b][m][w][c] bf16. grid (64 m, 4 b), 256 thr.
__global__ __launch_bounds__(256) void k4a(const float* __restrict__ out1,
                                           const float* __restrict__ s1,
                                           const float* __restrict__ sh1,
                                           u16* __restrict__ yT) {
  int m = blockIdx.x, b = blockIdx.y;
  __shared__ __align__(16) u16 T2[64 * 136];
  int t = threadIdx.x;
  for (int e = t; e < 2048; e += 256) {
    int w4 = e & 15, c = e >> 4;
    float4 r = *(const float4*)&out1[((b * COUTC + c) * HH + m) * WW + w4 * 4];
    float sc = s1[c], sh = sh1[c];
    T2[(w4 * 4 + 0) * 136 + c] = f2bf(fmaxf(fmaf(r.x, sc, sh), 0.f));
    T2[(w4 * 4 + 1) * 136 + c] = f2bf(fmaxf(fmaf(r.y, sc, sh), 0.f));
    T2[(w4 * 4 + 2) * 136 + c] = f2bf(fmaxf(fmaf(r.z, sc, sh), 0.f));
    T2[(w4 * 4 + 3) * 136 + c] = f2bf(fmaxf(fmaf(r.w, sc, sh), 0.f));
  }
  __syncthreads();
  for (int e = t; e < 1024; e += 256) {
    int g2 = e * 8;
    int w = g2 >> 7, i = g2 & 127;
    *(bf16x8*)&yT[((size_t)(b * 64 + m) * 64 + w) * 128 + i] =
        *(const bf16x8*)&T2[w * 136 + i];
  }
}

// ---------------- K4m: transposed conv as bf16 MFMA GEMM.
__global__ __launch_bounds__(256) void k4m(const u16* __restrict__ yT,
                                           const u16* __restrict__ Apk,
                                           float* __restrict__ out2) {
  int oh = blockIdx.x, b = blockIdx.y;
  int a = oh >> 1, p = oh & 1;
  __shared__ __align__(16) u16 T[2][66 * 136];
  int t = threadIdx.x;
  int wave = t >> 6, lane15 = t & 15, quad = (t >> 4) & 3;

  // zero border cols: 2 bufs x 2 cols x 128 ch
  for (int e = t; e < 512; e += 256) {
    int ky = e >> 8;
    int rem = e & 255;
    int colp = (rem >> 7) * 65;
    int i = rem & 127;
    T[ky][colp * 136 + i] = 0;
  }
  // stage both tap rows (r = a+p+ky-1); contiguous 16KB copy each
#pragma unroll
  for (int ky = 0; ky < 2; ky++) {
    int r = a + p + ky - 1;
    bool ok = ((unsigned)r < 64u);
    const u16* src = yT + ((size_t)(b * 64 + r) * 64) * 128;
#pragma unroll
    for (int it = 0; it < 4; it++) {
      int g2 = (it * 256 + t) * 8;
      int col = g2 >> 7, i = g2 & 127;
      bf16x8 v = (bf16x8){0, 0, 0, 0, 0, 0, 0, 0};
      if (ok) v = *(const bf16x8*)(src + g2);
      *(bf16x8*)&T[ky][(col + 1) * 136 + i] = v;
    }
  }
  __syncthreads();

  f32x4 acc[2][2][4];  // [q][tr][pc]
#pragma unroll
  for (int q = 0; q < 2; q++)
#pragma unroll
    for (int tr = 0; tr < 2; tr++)
#pragma unroll
      for (int pc = 0; pc < 4; pc++) acc[q][tr][pc] = (f32x4){0.f, 0.f, 0.f, 0.f};

  int row0 = wave * 32 + lane15;
  const u16* A0 = Apk + ((size_t)(p * 2 + 0) * 128) * 512;
  const u16* A1 = Apk + ((size_t)(p * 2 + 1) * 128) * 512;

#pragma unroll
  for (int ky = 0; ky < 2; ky++)
#pragma unroll
    for (int kx = 0; kx < 2; kx++)
#pragma unroll
      for (int c4 = 0; c4 < 4; c4++) {
        int kb = (ky * 2 + kx) * 128 + c4 * 32 + quad * 8;
        bf16x8 a00 = *(const bf16x8*)(A0 + (size_t)row0 * 512 + kb);
        bf16x8 a01 = *(const bf16x8*)(A0 + (size_t)(row0 + 16) * 512 + kb);
        bf16x8 a10 = *(const bf16x8*)(A1 + (size_t)row0 * 512 + kb);
        bf16x8 a11 = *(const bf16x8*)(A1 + (size_t)(row0 + 16) * 512 + kb);
        const u16* tb = &T[ky][(lane15 + kx) * 136 + c4 * 32 + quad * 8];
#pragma unroll
        for (int pc = 0; pc < 4; pc++) {
          bf16x8 b0 = *(const bf16x8*)(tb + (pc * 16) * 136);
          bf16x8 b1 = *(const bf16x8*)(tb + (pc * 16 + 1) * 136);
          acc[0][0][pc] = __builtin_amdgcn_mfma_f32_16x16x32_bf16(a00, b0, acc[0][0][pc], 0, 0, 0);
          acc[0][1][pc] = __builtin_amdgcn_mfma_f32_16x16x32_bf16(a01, b0, acc[0][1][pc], 0, 0, 0);
          acc[1][0][pc] = __builtin_amdgcn_mfma_f32_16x16x32_bf16(a10, b1, acc[1][0][pc], 0, 0, 0);
          acc[1][1][pc] = __builtin_amdgcn_mfma_f32_16x16x32_bf16(a11, b1, acc[1][1][pc], 0, 0, 0);
        }
      }

  // epilogue: C/D col=lane&15 (px), row=quad*4+i (cout). ow = 2*px + q -> float2.
#pragma unroll
  for (int tr = 0; tr < 2; tr++) {
    int o0 = wave * 32 + tr * 16 + quad * 4;
#pragma unroll
    for (int pc = 0; pc < 4; pc++) {
      f32x4 v0 = acc[0][tr][pc];
      f32x4 v1 = acc[1][tr][pc];
      int cw = pc * 32 + 2 * lane15;
#pragma unroll
      for (int i = 0; i < 4; i++) {
        float2 w2;
        w2.x = v0[i];
        w2.y = v1[i];
        *(float2*)&out2[(((size_t)b * COUTC + o0 + i) * OHH + oh) * OWW + cw] = w2;
      }
    }
  }
}

// ---------------- K6: bn2+relu apply (f32 out)
__global__ __launch_bounds__(256) void k6s(const float* __restrict__ out2,
                                           const float* __restrict__ scale2,
                                           const float* __restrict__ shift2,
                                           float* __restrict__ outp) {
  int tid = blockIdx.x * 256 + threadIdx.x;
  if (tid >= BB * COUTC * OHH * OWW) return;
  int c = (tid >> 14) & 127;
  outp[tid] = fmaxf(fmaf(out2[tid], scale2[c], shift2[c]), 0.f);
}

// ---------------- launch
extern "C" void kernel_launch(void* const* d_in, const int* in_sizes, int n_in,
                              void* d_out, int out_size, void* d_ws, size_t ws_size,
                              hipStream_t stream) {
  const float* x     = (const float*)d_in[0];
  const float* off_w = (const float*)d_in[1];
  const float* off_b = (const float*)d_in[2];
  const float* dcn_w = (const float*)d_in[3];
  const float* dcn_b = (const float*)d_in[4];
  const float* bn1_g = (const float*)d_in[5];
  const float* bn1_b = (const float*)d_in[6];
  const float* up_w  = (const float*)d_in[7];
  const float* bn2_g = (const float*)d_in[8];
  const float* bn2_b = (const float*)d_in[9];

  float* ws = (float*)d_ws;
  float* pyg  = ws;                              // 147456
  float* pxg  = pyg + BB * 9 * HH * WW;          // 147456
  float* mg   = pxg + BB * 9 * HH * WW;          // 147456
  float* out1 = mg + BB * 9 * HH * WW;           // 2097152
  float* scale1 = out1 + BB * COUTC * HH * WW;   // 128
  float* shift1 = scale1 + 128;                  // 128
  float* out2 = shift1 + 128;                    // 8388608
  float* scale2 = out2 + BB * COUTC * OHH * OWW; // 128
  float* shift2 = scale2 + 128;                  // 128
  float* w_t = shift2 + 128;                     // 294912 floats reserved (wA uses half as u16)
  float* wt4 = w_t + COUTC * CINC * 9;           // 262144 floats (Apk uses as u16)
  float* part2 = wt4 + 4 * COUTC * COUTC * 4;    // 4 * 2097152
  u16* wA = (u16*)w_t;                           // 128*2304 bf16
  u16* Apk = (u16*)wt4;                          // 4*128*512 bf16 = 512KB
  // k1 partials (8*4*27*4096 = 3.5M floats) overlaid on out2 region
  float* part = out2;
  // xT (f32 channel-last, 4.19M floats) overlaid on out2 region too:
  // lifetime k2t..k2m, dead before k4m writes out2. part is dead after k1r.
  float* xT = out2;
  // bn stats partials overlaid on part2 start (dead after k2r)
  float* psum = part2;            // up to 128*16
  float* pssq = part2 + 128 * 16; // up to 128*16
  // yT (bf16 4MB) overlaid past the stats partials in the part2 region
  u16* yT = (u16*)(part2 + 8192);

  const int N4 = BB * COUTC * OHH * OWW;  // 8388608
  const int N2 = BB * COUTC * HH * WW;    // 2097152
  const int N1 = BB * 27 * HH * WW;       // 442368

  k0t<<<(COUTC * CINC * 9 + 255) / 256, 256, 0, stream>>>(dcn_w, wA);
  k4w<<<(4 * COUTC * 512 + 255) / 256, 256, 0, stream>>>(up_w, Apk);
  k1p<<<dim3(8, 64, 4), 256, 0, stream>>>(x, off_w, part);
  k1r<<<(N1 + 255) / 256, 256, 0, stream>>>(part, off_b, pyg, pxg, mg);
  // channel-last transpose of x (into out2 region, after k1r consumed `part`)
  k2t<<<dim3(64, 4, 4), 256, 0, stream>>>(x, xT);
  k2m<<<dim3(4, 64, 4), 256, 0, stream>>>(xT, wA, pyg, pxg, mg, part2);
  k2r<<<(N2 + 255) / 256, 256, 0, stream>>>(part2, dcn_b, out1);
  // bn1 stats
  bn_part<1024, 8><<<dim3(COUTC, 8), 256, 0, stream>>>(out1, psum, pssq);
  bn_fin<<<1, 128, 0, stream>>>(psum, pssq, bn1_g, bn1_b, scale1, shift1, 8,
                                1.f / 16384.f);
  // bn1 apply + transpose to bf16 channel-last
  k4a<<<dim3(64, 4), 256, 0, stream>>>(out1, scale1, shift1, yT);
  // transposed conv via MFMA
  k4m<<<dim3(128, 4), 256, 0, stream>>>(yT, Apk, out2);
  // bn2 stats
  bn_part<4096, 16><<<dim3(COUTC, 16), 256, 0, stream>>>(out2, psum, pssq);
  bn_fin<<<1, 128, 0, stream>>>(psum, pssq, bn2_g, bn2_b, scale2, shift2, 16,
                                1.f / 65536.f);
  k6s<<<(N4 + 255) / 256, 256, 0, stream>>>(out2, scale2, shift2, (float*)d_out);
}

// Round 4
// 296.353 us; speedup vs baseline: 1.9527x; 1.0989x over previous
//
#include <hip/hip_runtime.h>
#include <math.h>

// Problem constants
#define BB 4
#define CINC 256
#define COUTC 128
#define HH 64
#define WW 64
#define OHH 128
#define OWW 128

typedef unsigned short u16;
typedef __attribute__((ext_vector_type(8))) short bf16x8;
typedef __attribute__((ext_vector_type(4))) float f32x4;

__device__ __forceinline__ u16 f2bf(float f) {
  unsigned int u = __float_as_uint(f);
  unsigned int r = u + 0x7FFFu + ((u >> 16) & 1u);  // RNE
  return (u16)(r >> 16);
}

// ---------------- K0t: dcn_w [o][c*9+q] -> bf16 wA[o][q*256+c]  (K reordered so a
// 32-wide K-chunk has constant tap q; contiguous k for MFMA A-frags)
__global__ __launch_bounds__(256) void k0t(const float* __restrict__ dcn_w, u16* __restrict__ wA) {
  int tid = blockIdx.x * 256 + threadIdx.x;
  if (tid >= COUTC * CINC * 9) return;
  int o = tid / 2304;
  int ckr = tid - o * 2304;
  int q = ckr >> 8;
  int c = ckr & 255;
  wA[tid] = f2bf(dcn_w[o * 2304 + c * 9 + q]);
}

// ---------------- K0o: off_w -> hi/lo bf16 split, padded to 32 rows.
// wOk[row][q*256+c] hi at [0, 73728), lo at [73728, 147456). rows 27..31 = 0.
__global__ __launch_bounds__(256) void k0o(const float* __restrict__ off_w, u16* __restrict__ wOk) {
  int tid = blockIdx.x * 256 + threadIdx.x;
  if (tid >= 32 * 2304) return;
  int row = tid / 2304;
  int kr = tid - row * 2304;
  int q = kr >> 8, c = kr & 255;
  float w = (row < 27) ? off_w[(row * CINC + c) * 9 + q] : 0.f;
  u16 hi = f2bf(w);
  float hf = __uint_as_float((unsigned)hi << 16);
  u16 lo = f2bf(w - hf);
  wOk[tid] = hi;
  wOk[73728 + tid] = lo;
}

// ---------------- K4w: pack up_w into 4 parity-class bf16 A-matrices.
// Apk[pq][o][k'], k' = (ky*2+kx)*128 + i  (tap-major: each 32-K chunk tap-uniform).
__global__ __launch_bounds__(256) void k4w(const float* __restrict__ up_w, u16* __restrict__ Apk) {
  int tid = blockIdx.x * 256 + threadIdx.x;
  if (tid >= 4 * COUTC * 512) return;
  int kp = tid & 511;
  int o = (tid >> 9) & 127;
  int pq = tid >> 16;
  int p = pq >> 1, q = pq & 1;
  int ky = kp >> 8, kx = (kp >> 7) & 1, i = kp & 127;
  float v = up_w[((i * COUTC + o) * 4 + (3 - (p + 2 * ky))) * 4 + (3 - (q + 2 * kx))];
  Apk[tid] = f2bf(v);
}

// ---------------- K2t: transpose x[b][c][y][w] -> xT[b][y][w][c] (f32, channel-last).
// grid (64 y, 4 cq, 4 b), 256 thr. LDS 64x65 tile; both sides coalesced 256B.
__global__ __launch_bounds__(256) void k2t(const float* __restrict__ x, float* __restrict__ xT) {
  int y = blockIdx.x, cq = blockIdx.y, b = blockIdx.z;
  __shared__ float tile[64][65];
  int t = threadIdx.x;
  int tx = t & 63;
  int tg = t >> 6;
#pragma unroll
  for (int i = 0; i < 16; i++) {
    int c = tg * 16 + i;
    tile[c][tx] = x[((size_t)(b * CINC + cq * 64 + c) * HH + y) * WW + tx];
  }
  __syncthreads();
#pragma unroll
  for (int i = 0; i < 16; i++) {
    int xc = tg * 16 + i;
    xT[((size_t)(b * HH + y) * WW + xc) * CINC + cq * 64 + tx] = tile[tx][xc];
  }
}

// ---------------- K1m: offset conv as MFMA GEMM, fused bias+transform epilogue.
// grid (64 h, 4 b), 256 thr = 4 waves; wave = px-tile of 16. M=32 (27 used),
// K=2304 (tap-major k=q*256+c), B-frags loaded DIRECTLY from channel-last xT
// (8 contiguous ch per lane, no LDS/barrier). hi/lo bf16 split on both operands
// (3-term MFMA) keeps offsets at ~f32 accuracy. Epilogue: bias + py/px/sigmoid.
__global__ __launch_bounds__(256) void k1m(const float* __restrict__ xT,
                                           const u16* __restrict__ wOk,
                                           const float* __restrict__ off_b,
                                           float* __restrict__ pyg,
                                           float* __restrict__ pxg,
                                           float* __restrict__ mg) {
  int h = blockIdx.x, b = blockIdx.y;
  int t = threadIdx.x;
  int pt = t >> 6;
  int lane15 = t & 15;
  int quad = (t >> 4) & 3;

  const u16* wh0 = wOk + (size_t)lane15 * 2304 + quad * 8;
  const u16* wh1 = wh0 + 16 * 2304;
  const u16* wl0 = wh0 + 73728;
  const u16* wl1 = wh1 + 73728;

  f32x4 acc[2];
  acc[0] = (f32x4){0.f, 0.f, 0.f, 0.f};
  acc[1] = (f32x4){0.f, 0.f, 0.f, 0.f};

  for (int q = 0; q < 9; q++) {
    int y = h + q / 3 - 1;
    if ((unsigned)y >= 64u) continue;
    int xc = pt * 16 + lane15 + (q % 3) - 1;
    bool xok = (unsigned)xc < 64u;
    int xcc = min(max(xc, 0), 63);
    const float* bsrc = xT + (((size_t)(b * 64 + y) * 64 + xcc) * 256) + quad * 8;
#pragma unroll
    for (int c8 = 0; c8 < 8; c8++) {
      f32x4 v0 = *(const f32x4*)(bsrc + c8 * 32);
      f32x4 v1 = *(const f32x4*)(bsrc + c8 * 32 + 4);
      if (!xok) {
        v0 = (f32x4){0.f, 0.f, 0.f, 0.f};
        v1 = (f32x4){0.f, 0.f, 0.f, 0.f};
      }
      bf16x8 xh, xl;
#pragma unroll
      for (int j = 0; j < 4; j++) {
        u16 hv = f2bf(v0[j]);
        xh[j] = (short)hv;
        xl[j] = (short)f2bf(v0[j] - __uint_as_float((unsigned)hv << 16));
        u16 hv2 = f2bf(v1[j]);
        xh[4 + j] = (short)hv2;
        xl[4 + j] = (short)f2bf(v1[j] - __uint_as_float((unsigned)hv2 << 16));
      }
      int kk = (q * 8 + c8) * 32;
      bf16x8 ah0 = *(const bf16x8*)(wh0 + kk);
      bf16x8 ah1 = *(const bf16x8*)(wh1 + kk);
      bf16x8 al0 = *(const bf16x8*)(wl0 + kk);
      bf16x8 al1 = *(const bf16x8*)(wl1 + kk);
      acc[0] = __builtin_amdgcn_mfma_f32_16x16x32_bf16(ah0, xh, acc[0], 0, 0, 0);
      acc[0] = __builtin_amdgcn_mfma_f32_16x16x32_bf16(ah0, xl, acc[0], 0, 0, 0);
      acc[0] = __builtin_amdgcn_mfma_f32_16x16x32_bf16(al0, xh, acc[0], 0, 0, 0);
      acc[1] = __builtin_amdgcn_mfma_f32_16x16x32_bf16(ah1, xh, acc[1], 0, 0, 0);
      acc[1] = __builtin_amdgcn_mfma_f32_16x16x32_bf16(ah1, xl, acc[1], 0, 0, 0);
      acc[1] = __builtin_amdgcn_mfma_f32_16x16x32_bf16(al1, xh, acc[1], 0, 0, 0);
    }
  }

  // epilogue: C/D col=lane15 (px), row=quad*4+i (oc); fuse bias + transform
  int px = pt * 16 + lane15;
#pragma unroll
  for (int tr = 0; tr < 2; tr++) {
#pragma unroll
    for (int i = 0; i < 4; i++) {
      int oc = tr * 16 + quad * 4 + i;
      if (oc >= 27) continue;
      float v = acc[tr][i] + off_b[oc];
      if (oc < 9) {
        pyg[((b * 9 + oc) * 64 + h) * 64 + px] = v + (float)(oc / 3) - 1.f + (float)h;
      } else if (oc < 18) {
        int k = oc - 9;
        pxg[((b * 9 + k) * 64 + h) * 64 + px] = v + (float)(k % 3) - 1.f + (float)px;
      } else {
        int k = oc - 18;
        mg[((b * 9 + k) * 64 + h) * 64 + px] = 1.f / (1.f + expf(-v));
      }
    }
  }
}

// ---------------- gather: 4 corners x 8 contiguous channels from channel-last xT.
__device__ __forceinline__ void gatherC(const float* __restrict__ base,
                                        int sA0, int sA1, int sB0, int sB1,
                                        f32x4* rx) {
  const float* pA0 = base + (size_t)sA0 * CINC;
  const float* pA1 = base + (size_t)sA1 * CINC;
  const float* pB0 = base + (size_t)sB0 * CINC;
  const float* pB1 = base + (size_t)sB1 * CINC;
  rx[0] = *(const f32x4*)pA0;
  rx[1] = *(const f32x4*)(pA0 + 4);
  rx[2] = *(const f32x4*)pA1;
  rx[3] = *(const f32x4*)(pA1 + 4);
  rx[4] = *(const f32x4*)pB0;
  rx[5] = *(const f32x4*)(pB0 + 4);
  rx[6] = *(const f32x4*)pB1;
  rx[7] = *(const f32x4*)(pB1 + 4);
}

// ---------------- K2m: deformable conv, split-K(4), bf16 MFMA GEMM.
__global__ __launch_bounds__(256) void k2m(const float* __restrict__ xT,
                                           const u16* __restrict__ wA,
                                           const float* __restrict__ pyg,
                                           const float* __restrict__ pxg,
                                           const float* __restrict__ mg,
                                           float* __restrict__ part2) {
  int ks = blockIdx.x, h = blockIdx.y, b = blockIdx.z;
  __shared__ __align__(16) u16 scolT[2][64 * 40];  // [px][ck] bf16, +8 pad
  int t = threadIdx.x;
  int px = t & 63;
  int wave = t >> 6;
  int lane15 = t & 15;
  int quad = (t >> 4) & 3;

  // ---- per-(q,px) bilinear descriptors (masked, m-premultiplied) ----
  float dw0[9], dw1[9], dw2[9], dw3[9];
  int doA[9], doB[9];
#pragma unroll
  for (int q = 0; q < 9; q++) {
    int gi = ((b * 9 + q) * HH + h) * WW + px;
    float py = pyg[gi], pxx = pxg[gi], m = mg[gi];
    float y0f = floorf(py), x0f = floorf(pxx);
    float wy = py - y0f, wx = pxx - x0f;
    int y0 = (int)y0f, x0 = (int)x0f;
    bool vy0 = (unsigned)y0 < 64u, vy1 = (unsigned)(y0 + 1) < 64u;
    bool vx0 = (unsigned)x0 < 64u, vx1 = (unsigned)(x0 + 1) < 64u;
    int y0c = min(max(y0, 0), 63), y1c = min(max(y0 + 1, 0), 63);
    int x0c = min(max(x0, 0), 63), x1c = min(max(x0 + 1, 0), 63);
    dw0[q] = (vy0 && vx0) ? (1.f - wy) * (1.f - wx) * m : 0.f;
    dw1[q] = (vy0 && vx1) ? (1.f - wy) * wx * m : 0.f;
    dw2[q] = (vy1 && vx0) ? wy * (1.f - wx) * m : 0.f;
    dw3[q] = (vy1 && vx1) ? wy * wx * m : 0.f;
    doA[q] = (y0c * 64 + x0c) | ((y0c * 64 + x1c) << 16);
    doB[q] = (y1c * 64 + x0c) | ((y1c * 64 + x1c) << 16);
  }

  f32x4 acc[8];
#pragma unroll
  for (int i = 0; i < 8; i++) acc[i] = (f32x4){0.f, 0.f, 0.f, 0.f};

  const float* xTb = xT + (size_t)b * 4096 * CINC;
  const u16* wAr0 = wA + (wave * 32 + lane15) * 2304 + quad * 8;
  const u16* wAr1 = wAr0 + 16 * 2304;

  f32x4 rx[8];
  // prefetch chunk 0 (q=0, channels ks*64 + wave*8)
  gatherC(xTb + ks * 64 + wave * 8, doA[0] & 0xffff, ((unsigned)doA[0]) >> 16,
          doB[0] & 0xffff, ((unsigned)doB[0]) >> 16, rx);

#pragma unroll
  for (int ci = 0; ci < 18; ci++) {
    int q = ci >> 1;
    // combine prefetched corner vectors -> bf16 pack -> one b128 LDS write
    float v[8];
#pragma unroll
    for (int j = 0; j < 4; j++) {
      v[j]     = dw0[q] * rx[0][j] + dw1[q] * rx[2][j] + dw2[q] * rx[4][j] + dw3[q] * rx[6][j];
      v[4 + j] = dw0[q] * rx[1][j] + dw1[q] * rx[3][j] + dw2[q] * rx[5][j] + dw3[q] * rx[7][j];
    }
    uint4 st;
    st.x = (unsigned)f2bf(v[0]) | ((unsigned)f2bf(v[1]) << 16);
    st.y = (unsigned)f2bf(v[2]) | ((unsigned)f2bf(v[3]) << 16);
    st.z = (unsigned)f2bf(v[4]) | ((unsigned)f2bf(v[5]) << 16);
    st.w = (unsigned)f2bf(v[6]) | ((unsigned)f2bf(v[7]) << 16);
    *(uint4*)&scolT[ci & 1][px * 40 + wave * 8] = st;

    // issue next chunk's gathers (land during barrier+MFMA)
    if (ci < 17) {
      int qn = (ci + 1) >> 1;
      int c0n = ks * 64 + ((ci + 1) & 1) * 32 + wave * 8;
      gatherC(xTb + c0n, doA[qn] & 0xffff, ((unsigned)doA[qn]) >> 16,
              doB[qn] & 0xffff, ((unsigned)doB[qn]) >> 16, rx);
    }
    __syncthreads();  // buf[ci&1] visible; prev reads of buf[(ci-1)&1] drained
    // MFMA: 2 cout rows x 4 px tiles
    int kb = q * 256 + ks * 64 + (ci & 1) * 32;
    bf16x8 a0 = *(const bf16x8*)(wAr0 + kb);
    bf16x8 a1 = *(const bf16x8*)(wAr1 + kb);
    const u16* sr = &scolT[ci & 1][lane15 * 40 + quad * 8];
    bf16x8 b0 = *(const bf16x8*)(sr);
    bf16x8 b1 = *(const bf16x8*)(sr + 16 * 40);
    bf16x8 b2 = *(const bf16x8*)(sr + 32 * 40);
    bf16x8 b3 = *(const bf16x8*)(sr + 48 * 40);
    acc[0] = __builtin_amdgcn_mfma_f32_16x16x32_bf16(a0, b0, acc[0], 0, 0, 0);
    acc[1] = __builtin_amdgcn_mfma_f32_16x16x32_bf16(a0, b1, acc[1], 0, 0, 0);
    acc[2] = __builtin_amdgcn_mfma_f32_16x16x32_bf16(a0, b2, acc[2], 0, 0, 0);
    acc[3] = __builtin_amdgcn_mfma_f32_16x16x32_bf16(a0, b3, acc[3], 0, 0, 0);
    acc[4] = __builtin_amdgcn_mfma_f32_16x16x32_bf16(a1, b0, acc[4], 0, 0, 0);
    acc[5] = __builtin_amdgcn_mfma_f32_16x16x32_bf16(a1, b1, acc[5], 0, 0, 0);
    acc[6] = __builtin_amdgcn_mfma_f32_16x16x32_bf16(a1, b2, acc[6], 0, 0, 0);
    acc[7] = __builtin_amdgcn_mfma_f32_16x16x32_bf16(a1, b3, acc[7], 0, 0, 0);
  }

  // write partials: part2[ks][b][o][h][w]; C/D: col=lane&15 (px), row=quad*4+i (o)
  float* pb = part2 + (size_t)ks * BB * COUTC * 4096;
#pragma unroll
  for (int tr = 0; tr < 2; tr++)
#pragma unroll
    for (int pc = 0; pc < 4; pc++) {
      f32x4 a = acc[tr * 4 + pc];
      int ob = wave * 32 + tr * 16 + quad * 4;
#pragma unroll
      for (int i = 0; i < 4; i++)
        pb[((b * COUTC + ob + i) * HH + h) * WW + pc * 16 + lane15] = a[i];
    }
}

// ---------------- K2r: sum 4 partials + bias -> out1
__global__ __launch_bounds__(256) void k2r(const float* __restrict__ part2,
                                           const float* __restrict__ dcn_b,
                                           float* __restrict__ out1) {
  int tid = blockIdx.x * 256 + threadIdx.x;
  if (tid >= BB * COUTC * HH * WW) return;
  int o = (tid >> 12) & 127;
  const int S = BB * COUTC * 4096;
  out1[tid] = part2[tid] + part2[tid + S] + part2[tid + 2 * S] + part2[tid + 3 * S] + dcn_b[o];
}

// ---------------- BN stats: single-pass split reduction (sum + sumsq).
template <int PLANEF4, int NCHUNK>
__global__ __launch_bounds__(256) void bn_part(const float* __restrict__ src,
                                               float* __restrict__ psum,
                                               float* __restrict__ pssq) {
  int c = blockIdx.x, chunk = blockIdx.y, t = threadIdx.x;
  constexpr int PER = (BB * PLANEF4) / NCHUNK;  // float4s per chunk
  float s = 0.f, s2 = 0.f;
#pragma unroll
  for (int i = 0; i < PER / 256; i++) {
    int f = chunk * PER + i * 256 + t;
    int b = f / PLANEF4;  // compile-time divisor -> shifts
    int sp = f - b * PLANEF4;
    const float4 v = *(const float4*)&src[((size_t)(b * COUTC + c) * PLANEF4 + sp) * 4];
    s += v.x + v.y + v.z + v.w;
    s2 += v.x * v.x + v.y * v.y + v.z * v.z + v.w * v.w;
  }
#pragma unroll
  for (int off = 32; off > 0; off >>= 1) {
    s += __shfl_down(s, off);
    s2 += __shfl_down(s2, off);
  }
  __shared__ float rs[4], rq[4];
  int wv = t >> 6;
  if ((t & 63) == 0) { rs[wv] = s; rq[wv] = s2; }
  __syncthreads();
  if (t == 0) {
    psum[c * NCHUNK + chunk] = rs[0] + rs[1] + rs[2] + rs[3];
    pssq[c * NCHUNK + chunk] = rq[0] + rq[1] + rq[2] + rq[3];
  }
}

// finalize: 1 block x 128 threads; per-channel scale/shift from partials
__global__ __launch_bounds__(128) void bn_fin(const float* __restrict__ psum,
                                              const float* __restrict__ pssq,
                                              const float* __restrict__ g,
                                              const float* __restrict__ bt,
                                              float* __restrict__ scale,
                                              float* __restrict__ shift,
                                              int nchunk, float invN) {
  int c = threadIdx.x;
  float S = 0.f, Q = 0.f;
  for (int i = 0; i < nchunk; i++) {
    S += psum[c * nchunk + i];
    Q += pssq[c * nchunk + i];
  }
  float mu = S * invN;
  float var = Q * invN - mu * mu;
  float sc = g[c] * rsqrtf(var + 1e-5f);
  scale[c] = sc;
  shift[c] = bt[c] - mu * sc;
}

// ---------------- K4a: bn1+relu apply, bf16 convert, channel-last transpose.
__global__ __launch_bounds__(256) void k4a(const float* __restrict__ out1,
                                           const float* __restrict__ s1,
                                           const float* __restrict__ sh1,
                                           u16* __restrict__ yT) {
  int m = blockIdx.x, b = blockIdx.y;
  __shared__ __align__(16) u16 T2[64 * 136];
  int t = threadIdx.x;
  for (int e = t; e < 2048; e += 256) {
    int w4 = e & 15, c = e >> 4;
    float4 r = *(const float4*)&out1[((b * COUTC + c) * HH + m) * WW + w4 * 4];
    float sc = s1[c], sh = sh1[c];
    T2[(w4 * 4 + 0) * 136 + c] = f2bf(fmaxf(fmaf(r.x, sc, sh), 0.f));
    T2[(w4 * 4 + 1) * 136 + c] = f2bf(fmaxf(fmaf(r.y, sc, sh), 0.f));
    T2[(w4 * 4 + 2) * 136 + c] = f2bf(fmaxf(fmaf(r.z, sc, sh), 0.f));
    T2[(w4 * 4 + 3) * 136 + c] = f2bf(fmaxf(fmaf(r.w, sc, sh), 0.f));
  }
  __syncthreads();
  for (int e = t; e < 1024; e += 256) {
    int g2 = e * 8;
    int w = g2 >> 7, i = g2 & 127;
    *(bf16x8*)&yT[((size_t)(b * 64 + m) * 64 + w) * 128 + i] =
        *(const bf16x8*)&T2[w * 136 + i];
  }
}

// ---------------- K4m: transposed conv as bf16 MFMA GEMM.
__global__ __launch_bounds__(256) void k4m(const u16* __restrict__ yT,
                                           const u16* __restrict__ Apk,
                                           float* __restrict__ out2) {
  int oh = blockIdx.x, b = blockIdx.y;
  int a = oh >> 1, p = oh & 1;
  __shared__ __align__(16) u16 T[2][66 * 136];
  int t = threadIdx.x;
  int wave = t >> 6, lane15 = t & 15, quad = (t >> 4) & 3;

  // zero border cols: 2 bufs x 2 cols x 128 ch
  for (int e = t; e < 512; e += 256) {
    int ky = e >> 8;
    int rem = e & 255;
    int colp = (rem >> 7) * 65;
    int i = rem & 127;
    T[ky][colp * 136 + i] = 0;
  }
  // stage both tap rows (r = a+p+ky-1); contiguous 16KB copy each
#pragma unroll
  for (int ky = 0; ky < 2; ky++) {
    int r = a + p + ky - 1;
    bool ok = ((unsigned)r < 64u);
    const u16* src = yT + ((size_t)(b * 64 + r) * 64) * 128;
#pragma unroll
    for (int it = 0; it < 4; it++) {
      int g2 = (it * 256 + t) * 8;
      int col = g2 >> 7, i = g2 & 127;
      bf16x8 v = (bf16x8){0, 0, 0, 0, 0, 0, 0, 0};
      if (ok) v = *(const bf16x8*)(src + g2);
      *(bf16x8*)&T[ky][(col + 1) * 136 + i] = v;
    }
  }
  __syncthreads();

  f32x4 acc[2][2][4];  // [q][tr][pc]
#pragma unroll
  for (int q = 0; q < 2; q++)
#pragma unroll
    for (int tr = 0; tr < 2; tr++)
#pragma unroll
      for (int pc = 0; pc < 4; pc++) acc[q][tr][pc] = (f32x4){0.f, 0.f, 0.f, 0.f};

  int row0 = wave * 32 + lane15;
  const u16* A0 = Apk + ((size_t)(p * 2 + 0) * 128) * 512;
  const u16* A1 = Apk + ((size_t)(p * 2 + 1) * 128) * 512;

#pragma unroll
  for (int ky = 0; ky < 2; ky++)
#pragma unroll
    for (int kx = 0; kx < 2; kx++)
#pragma unroll
      for (int c4 = 0; c4 < 4; c4++) {
        int kb = (ky * 2 + kx) * 128 + c4 * 32 + quad * 8;
        bf16x8 a00 = *(const bf16x8*)(A0 + (size_t)row0 * 512 + kb);
        bf16x8 a01 = *(const bf16x8*)(A0 + (size_t)(row0 + 16) * 512 + kb);
        bf16x8 a10 = *(const bf16x8*)(A1 + (size_t)row0 * 512 + kb);
        bf16x8 a11 = *(const bf16x8*)(A1 + (size_t)(row0 + 16) * 512 + kb);
        const u16* tb = &T[ky][(lane15 + kx) * 136 + c4 * 32 + quad * 8];
#pragma unroll
        for (int pc = 0; pc < 4; pc++) {
          bf16x8 b0 = *(const bf16x8*)(tb + (pc * 16) * 136);
          bf16x8 b1 = *(const bf16x8*)(tb + (pc * 16 + 1) * 136);
          acc[0][0][pc] = __builtin_amdgcn_mfma_f32_16x16x32_bf16(a00, b0, acc[0][0][pc], 0, 0, 0);
          acc[0][1][pc] = __builtin_amdgcn_mfma_f32_16x16x32_bf16(a01, b0, acc[0][1][pc], 0, 0, 0);
          acc[1][0][pc] = __builtin_amdgcn_mfma_f32_16x16x32_bf16(a10, b1, acc[1][0][pc], 0, 0, 0);
          acc[1][1][pc] = __builtin_amdgcn_mfma_f32_16x16x32_bf16(a11, b1, acc[1][1][pc], 0, 0, 0);
        }
      }

  // epilogue: C/D col=lane&15 (px), row=quad*4+i (cout). ow = 2*px + q -> float2.
#pragma unroll
  for (int tr = 0; tr < 2; tr++) {
    int o0 = wave * 32 + tr * 16 + quad * 4;
#pragma unroll
    for (int pc = 0; pc < 4; pc++) {
      f32x4 v0 = acc[0][tr][pc];
      f32x4 v1 = acc[1][tr][pc];
      int cw = pc * 32 + 2 * lane15;
#pragma unroll
      for (int i = 0; i < 4; i++) {
        float2 w2;
        w2.x = v0[i];
        w2.y = v1[i];
        *(float2*)&out2[(((size_t)b * COUTC + o0 + i) * OHH + oh) * OWW + cw] = w2;
      }
    }
  }
}

// ---------------- K6: bn2+relu apply (f32 out)
__global__ __launch_bounds__(256) void k6s(const float* __restrict__ out2,
                                           const float* __restrict__ scale2,
                                           const float* __restrict__ shift2,
                                           float* __restrict__ outp) {
  int tid = blockIdx.x * 256 + threadIdx.x;
  if (tid >= BB * COUTC * OHH * OWW) return;
  int c = (tid >> 14) & 127;
  outp[tid] = fmaxf(fmaf(out2[tid], scale2[c], shift2[c]), 0.f);
}

// ---------------- launch
extern "C" void kernel_launch(void* const* d_in, const int* in_sizes, int n_in,
                              void* d_out, int out_size, void* d_ws, size_t ws_size,
                              hipStream_t stream) {
  const float* x     = (const float*)d_in[0];
  const float* off_w = (const float*)d_in[1];
  const float* off_b = (const float*)d_in[2];
  const float* dcn_w = (const float*)d_in[3];
  const float* dcn_b = (const float*)d_in[4];
  const float* bn1_g = (const float*)d_in[5];
  const float* bn1_b = (const float*)d_in[6];
  const float* up_w  = (const float*)d_in[7];
  const float* bn2_g = (const float*)d_in[8];
  const float* bn2_b = (const float*)d_in[9];

  float* ws = (float*)d_ws;
  float* pyg  = ws;                              // 147456
  float* pxg  = pyg + BB * 9 * HH * WW;          // 147456
  float* mg   = pxg + BB * 9 * HH * WW;          // 147456
  float* out1 = mg + BB * 9 * HH * WW;           // 2097152
  float* scale1 = out1 + BB * COUTC * HH * WW;   // 128
  float* shift1 = scale1 + 128;                  // 128
  float* out2 = shift1 + 128;                    // 8388608
  float* scale2 = out2 + BB * COUTC * OHH * OWW; // 128
  float* shift2 = scale2 + 128;                  // 128
  float* w_t = shift2 + 128;                     // 294912 floats reserved
  float* wt4 = w_t + COUTC * CINC * 9;           // 262144 floats (Apk uses as u16)
  float* part2 = wt4 + 4 * COUTC * COUTC * 4;    // 4 * 2097152
  u16* wA = (u16*)w_t;                           // 128*2304 bf16 (first half of w_t region)
  u16* wOk = (u16*)(w_t + 147456);               // 2*32*2304 bf16 hi/lo (second half)
  u16* Apk = (u16*)wt4;                          // 4*128*512 bf16 = 512KB
  // xT (f32 channel-last, 4.19M floats) overlaid on out2 region:
  // lifetime k2t..k2m, dead before k4m writes out2.
  float* xT = out2;
  // bn stats partials overlaid on part2 start (dead after k2r)
  float* psum = part2;            // up to 128*16
  float* pssq = part2 + 128 * 16; // up to 128*16
  // yT (bf16 4MB) overlaid past the stats partials in the part2 region
  u16* yT = (u16*)(part2 + 8192);

  const int N4 = BB * COUTC * OHH * OWW;  // 8388608
  const int N2 = BB * COUTC * HH * WW;    // 2097152

  k0t<<<(COUTC * CINC * 9 + 255) / 256, 256, 0, stream>>>(dcn_w, wA);
  k0o<<<(32 * 2304 + 255) / 256, 256, 0, stream>>>(off_w, wOk);
  k4w<<<(4 * COUTC * 512 + 255) / 256, 256, 0, stream>>>(up_w, Apk);
  // channel-last transpose of x (into out2 region)
  k2t<<<dim3(64, 4, 4), 256, 0, stream>>>(x, xT);
  // offset conv via MFMA (fused bias + py/px/sigmoid epilogue)
  k1m<<<dim3(64, 4), 256, 0, stream>>>(xT, wOk, off_b, pyg, pxg, mg);
  k2m<<<dim3(4, 64, 4), 256, 0, stream>>>(xT, wA, pyg, pxg, mg, part2);
  k2r<<<(N2 + 255) / 256, 256, 0, stream>>>(part2, dcn_b, out1);
  // bn1 stats
  bn_part<1024, 8><<<dim3(COUTC, 8), 256, 0, stream>>>(out1, psum, pssq);
  bn_fin<<<1, 128, 0, stream>>>(psum, pssq, bn1_g, bn1_b, scale1, shift1, 8,
                                1.f / 16384.f);
  // bn1 apply + transpose to bf16 channel-last
  k4a<<<dim3(64, 4), 256, 0, stream>>>(out1, scale1, shift1, yT);
  // transposed conv via MFMA
  k4m<<<dim3(128, 4), 256, 0, stream>>>(yT, Apk, out2);
  // bn2 stats
  bn_part<4096, 16><<<dim3(COUTC, 16), 256, 0, stream>>>(out2, psum, pssq);
  bn_fin<<<1, 128, 0, stream>>>(psum, pssq, bn2_g, bn2_b, scale2, shift2, 16,
                                1.f / 65536.f);
  k6s<<<(N4 + 255) / 256, 256, 0, stream>>>(out2, scale2, shift2, (float*)d_out);
}